// Round 2
// baseline (1252.847 us; speedup 1.0000x reference)
//
#include <hip/hip_runtime.h>
#include <hip/hip_bf16.h>
#include <math.h>

// ---------------- helpers ----------------
__device__ __forceinline__ float lanebcast(float v, int l) {
  return __int_as_float(__builtin_amdgcn_readlane(__float_as_int(v), l));
}

__device__ __forceinline__ float wave_sum(float v) {
#pragma unroll
  for (int off = 32; off > 0; off >>= 1) v += __shfl_xor(v, off, 64);
  return v;
}

// ---------------- CSR build ----------------
__global__ void k_initdeg(int* deg, int n) {
  int i = blockIdx.x * blockDim.x + threadIdx.x;
  if (i < n) deg[i] = 1;  // self-loop
}

__global__ void k_count(const int* __restrict__ dst, int* deg, int E) {
  int e = blockIdx.x * blockDim.x + threadIdx.x;
  if (e < E) atomicAdd(&deg[dst[e]], 1);
}

// single-block exclusive scan
__global__ void k_scan(const int* __restrict__ deg, int* rowstart, int* cursor, int n) {
  __shared__ int smem[1024];
  __shared__ int carry_s;
  int tid = threadIdx.x;
  if (tid == 0) carry_s = 0;
  __syncthreads();
  const int PER = 8;
  for (int base = 0; base < n; base += 1024 * PER) {
    int vals[PER];
    int s = 0;
#pragma unroll
    for (int p = 0; p < PER; p++) {
      int i = base + tid * PER + p;
      int v = (i < n) ? deg[i] : 0;
      vals[p] = v;
      s += v;
    }
    smem[tid] = s;
    __syncthreads();
    for (int off = 1; off < 1024; off <<= 1) {
      int t = (tid >= off) ? smem[tid - off] : 0;
      __syncthreads();
      smem[tid] += t;
      __syncthreads();
    }
    int c = carry_s;
    int excl = smem[tid] - s + c;
    __syncthreads();
    if (tid == 1023) carry_s = c + smem[1023];
#pragma unroll
    for (int p = 0; p < PER; p++) {
      int i = base + tid * PER + p;
      if (i < n) { rowstart[i] = excl; cursor[i] = excl; }
      excl += vals[p];
    }
    __syncthreads();
  }
  if (tid == 0) rowstart[n] = carry_s;
}

__global__ void k_dinv(const int* __restrict__ deg, float* dinv, int n) {
  int i = blockIdx.x * blockDim.x + threadIdx.x;
  if (i < n) dinv[i] = 1.0f / sqrtf((float)deg[i]);
}

__global__ void k_scatter(const int* __restrict__ ei_src, const int* __restrict__ ei_dst,
                          int* cursor, int* colidx, int E, int n) {
  int e = blockIdx.x * blockDim.x + threadIdx.x;
  if (e >= E + n) return;
  int s, d;
  if (e < E) { s = ei_src[e]; d = ei_dst[e]; }
  else       { s = e - E; d = s; }
  int pos = atomicAdd(&cursor[d], 1);
  colidx[pos] = s;
}

// ---------------- K1: H0[N,64] = X[N,128] @ W0[128,64] ----------------
__global__ __launch_bounds__(256) void k_gemm0(
    const float* __restrict__ A, const float* __restrict__ W,
    float* __restrict__ H, int n) {
  __shared__ float lds_w[128 * 64];
  int tid = threadIdx.x;
  for (int idx = tid; idx < 128 * 64; idx += 256) lds_w[idx] = W[idx];
  __syncthreads();
  int wave = tid >> 6, lane = tid & 63;
  const int ROWS = 8;
  for (int rowbase = (blockIdx.x * 4 + wave) * ROWS; rowbase < n;
       rowbase += gridDim.x * 4 * ROWS) {
    float xr[ROWS][2];
#pragma unroll
    for (int r = 0; r < ROWS; r++) {
      int row = rowbase + r;
#pragma unroll
      for (int q = 0; q < 2; q++)
        xr[r][q] = (row < n) ? A[(size_t)row * 128 + q * 64 + lane] : 0.0f;
    }
    float acc[ROWS];
#pragma unroll
    for (int r = 0; r < ROWS; r++) acc[r] = 0.0f;
#pragma unroll
    for (int q = 0; q < 2; q++) {
#pragma unroll 8
      for (int kk = 0; kk < 64; kk++) {
        float wv = lds_w[(q * 64 + kk) * 64 + lane];
#pragma unroll
        for (int r = 0; r < ROWS; r++)
          acc[r] = fmaf(lanebcast(xr[r][q], kk), wv, acc[r]);
      }
    }
#pragma unroll
    for (int r = 0; r < ROWS; r++) {
      int row = rowbase + r;
      if (row < n) H[(size_t)row * 64 + lane] = acc[r];
    }
  }
}

// ---------------- K2/K3: fused GCN agg + next GEMM ----------------
// x_next = relu(dinv_n * sum_s dinv_s * h_in[s] + b); h_out = x_next @ Wn
__global__ __launch_bounds__(256) void k_agg_gemm(
    const float* __restrict__ h_in, const float* __restrict__ dinv,
    const int* __restrict__ rowstart, const int* __restrict__ colidx,
    const float* __restrict__ bias, const float* __restrict__ Wn,
    float* __restrict__ h_out, int n) {
  __shared__ float lds_w[64 * 64];
  int tid = threadIdx.x;
  for (int idx = tid; idx < 64 * 64; idx += 256) lds_w[idx] = Wn[idx];
  __syncthreads();
  int lane = tid & 63;
  float bv = bias[lane];
  int gw = blockIdx.x * 4 + (tid >> 6);
  int nw = gridDim.x * 4;
  for (int node = gw; node < n; node += nw) {
    int s0 = rowstart[node], s1 = rowstart[node + 1];
    float acc = 0.0f;
    int idx = s0;
    for (; idx + 1 < s1; idx += 2) {
      int sa = colidx[idx], sb = colidx[idx + 1];
      float va = h_in[(size_t)sa * 64 + lane];
      float vb = h_in[(size_t)sb * 64 + lane];
      acc = fmaf(dinv[sa], va, acc);
      acc = fmaf(dinv[sb], vb, acc);
    }
    if (idx < s1) {
      int sa = colidx[idx];
      acc = fmaf(dinv[sa], h_in[(size_t)sa * 64 + lane], acc);
    }
    float x1 = fmaxf(fmaf(dinv[node], acc, bv), 0.0f);
    float o = 0.0f;
#pragma unroll
    for (int k = 0; k < 64; k++)
      o = fmaf(lanebcast(x1, k), lds_w[k * 64 + lane], o);
    h_out[(size_t)node * 64 + lane] = o;
  }
}

// ---------------- K4: GCN layer-2 agg + GAT attention logits ----------------
// x3 = relu(agg + b2); a_src[n,h] = x3 . q_src[h]; a_dst likewise
__global__ __launch_bounds__(256) void k_agg_gatpre(
    const float* __restrict__ h_in, const float* __restrict__ dinv,
    const int* __restrict__ rowstart, const int* __restrict__ colidx,
    const float* __restrict__ bias,
    const float* __restrict__ q_src, const float* __restrict__ q_dst,
    float* __restrict__ x3, float* __restrict__ a_src, float* __restrict__ a_dst,
    int n) {
  int tid = threadIdx.x;
  int lane = tid & 63;
  float bv = bias[lane];
  float qs[4], qd[4];
#pragma unroll
  for (int h = 0; h < 4; h++) {
    qs[h] = q_src[h * 64 + lane];
    qd[h] = q_dst[h * 64 + lane];
  }
  int gw = blockIdx.x * 4 + (tid >> 6);
  int nw = gridDim.x * 4;
  for (int node = gw; node < n; node += nw) {
    int s0 = rowstart[node], s1 = rowstart[node + 1];
    float acc = 0.0f;
    int idx = s0;
    for (; idx + 1 < s1; idx += 2) {
      int sa = colidx[idx], sb = colidx[idx + 1];
      float va = h_in[(size_t)sa * 64 + lane];
      float vb = h_in[(size_t)sb * 64 + lane];
      acc = fmaf(dinv[sa], va, acc);
      acc = fmaf(dinv[sb], vb, acc);
    }
    if (idx < s1) {
      int sa = colidx[idx];
      acc = fmaf(dinv[sa], h_in[(size_t)sa * 64 + lane], acc);
    }
    float xv = fmaxf(fmaf(dinv[node], acc, bv), 0.0f);
    x3[(size_t)node * 64 + lane] = xv;
    float ps[4], pd[4];
#pragma unroll
    for (int h = 0; h < 4; h++) {
      ps[h] = wave_sum(xv * qs[h]);
      pd[h] = wave_sum(xv * qd[h]);
    }
    if (lane == 0) {
      *(float4*)&a_src[(size_t)node * 4] = make_float4(ps[0], ps[1], ps[2], ps[3]);
      *(float4*)&a_dst[(size_t)node * 4] = make_float4(pd[0], pd[1], pd[2], pd[3]);
    }
  }
}

// q[h][k] = sum_c W[k, h*64+c] * att[h][c]  (fold gat_w into att vectors)
__global__ void k_qpre(const float* __restrict__ W, const float* __restrict__ att_s,
                       const float* __restrict__ att_d,
                       float* __restrict__ q_src, float* __restrict__ q_dst) {
  int t = threadIdx.x;  // 256 threads: h = t/64, k = t%64
  int h = t >> 6, k = t & 63;
  float ss = 0.0f, sd = 0.0f;
  for (int c = 0; c < 64; c++) {
    float w = W[k * 256 + h * 64 + c];
    ss = fmaf(w, att_s[h * 64 + c], ss);
    sd = fmaf(w, att_d[h * 64 + c], sd);
  }
  q_src[h * 64 + k] = ss;
  q_dst[h * 64 + k] = sd;
}

// ---------------- K5: GAT aggregate on x3 + per-head GEMV epilogue ----------
// agg_h = sum_s exp(lrelu(a_src[s][h]+a_dst[n][h])) * x3[s]
// out = relu( (1/4) sum_h (agg_h / S_h) @ W_h + bias )
// W_gat staged in LDS as bf16, layout [k][lane][h] packed 2x per uint (32 KB).
__global__ __launch_bounds__(256) void k_gat_agg(
    const float* __restrict__ x3, const float* __restrict__ Wg,
    const float* __restrict__ a_src, const float* __restrict__ a_dst,
    const int* __restrict__ rowstart, const int* __restrict__ colidx,
    const float* __restrict__ bias, float* __restrict__ out, int n) {
  __shared__ unsigned int lds_wg[64 * 64 * 2];  // [k][lane][h0|h1, h2|h3]
  int tid = threadIdx.x;
  for (int p = tid; p < 64 * 64; p += 256) {
    int k = p >> 6, l = p & 63;
    unsigned int b0 = (__float_as_uint(Wg[k * 256 + 0 * 64 + l]) + 0x8000u) >> 16;
    unsigned int b1 = (__float_as_uint(Wg[k * 256 + 1 * 64 + l]) + 0x8000u) >> 16;
    unsigned int b2 = (__float_as_uint(Wg[k * 256 + 2 * 64 + l]) + 0x8000u) >> 16;
    unsigned int b3 = (__float_as_uint(Wg[k * 256 + 3 * 64 + l]) + 0x8000u) >> 16;
    lds_wg[p * 2 + 0] = b0 | (b1 << 16);
    lds_wg[p * 2 + 1] = b2 | (b3 << 16);
  }
  __syncthreads();
  int lane = tid & 63;
  float bv = bias[lane];
  int gw = blockIdx.x * 4 + (tid >> 6);
  int nw = gridDim.x * 4;
  for (int node = gw; node < n; node += nw) {
    const float4 adv = *(const float4*)&a_dst[(size_t)node * 4];
    int s0 = rowstart[node], s1 = rowstart[node + 1];
    float acc0 = 0, acc1 = 0, acc2 = 0, acc3 = 0;
    float S0 = 0, S1 = 0, S2 = 0, S3 = 0;
    for (int idx = s0; idx < s1; ++idx) {
      int s = colidx[idx];
      const float4 as = *(const float4*)&a_src[(size_t)s * 4];
      float e0 = as.x + adv.x; e0 = (e0 > 0.f) ? e0 : 0.2f * e0; float w0 = __expf(e0);
      float e1 = as.y + adv.y; e1 = (e1 > 0.f) ? e1 : 0.2f * e1; float w1 = __expf(e1);
      float e2 = as.z + adv.z; e2 = (e2 > 0.f) ? e2 : 0.2f * e2; float w2 = __expf(e2);
      float e3 = as.w + adv.w; e3 = (e3 > 0.f) ? e3 : 0.2f * e3; float w3 = __expf(e3);
      float v = x3[(size_t)s * 64 + lane];
      S0 += w0; S1 += w1; S2 += w2; S3 += w3;
      acc0 = fmaf(w0, v, acc0);
      acc1 = fmaf(w1, v, acc1);
      acc2 = fmaf(w2, v, acc2);
      acc3 = fmaf(w3, v, acc3);
    }
    // pre-scale by 0.25/S_h (S_h wave-uniform)
    acc0 *= 0.25f / S0; acc1 *= 0.25f / S1; acc2 *= 0.25f / S2; acc3 *= 0.25f / S3;
    float o = 0.0f;
#pragma unroll
    for (int k = 0; k < 64; k++) {
      uint2 u = *(const uint2*)&lds_wg[(k * 64 + lane) * 2];
      float w0 = __uint_as_float(u.x << 16);
      float w1 = __uint_as_float(u.x & 0xffff0000u);
      float w2 = __uint_as_float(u.y << 16);
      float w3 = __uint_as_float(u.y & 0xffff0000u);
      o = fmaf(lanebcast(acc0, k), w0, o);
      o = fmaf(lanebcast(acc1, k), w1, o);
      o = fmaf(lanebcast(acc2, k), w2, o);
      o = fmaf(lanebcast(acc3, k), w3, o);
    }
    out[(size_t)node * 64 + lane] = fmaxf(o + bv, 0.0f);
  }
}

// ---------------- pooling ----------------
__global__ void k_gstart(const int* __restrict__ batch, int* gs, int n, int B) {
  int g = blockIdx.x * blockDim.x + threadIdx.x;
  if (g > B) return;
  int lo = 0, hi = n;
  while (lo < hi) {
    int mid = (lo + hi) >> 1;
    if (batch[mid] < g) lo = mid + 1; else hi = mid;
  }
  gs[g] = lo;
}

__global__ __launch_bounds__(256) void k_pool(const float* __restrict__ x,
                                              const int* __restrict__ gs,
                                              float* __restrict__ gvec, int B) {
  int g = (blockIdx.x * blockDim.x + threadIdx.x) >> 6;
  int lane = threadIdx.x & 63;
  if (g >= B) return;
  int s0 = gs[g], s1 = gs[g + 1];
  float sum = 0.0f, mx = -INFINITY;
  for (int nd = s0; nd < s1; ++nd) {
    float v = x[(size_t)nd * 64 + lane];
    sum += v;
    mx = fmaxf(mx, v);
  }
  int cnt = s1 - s0;
  float mean = sum / fmaxf((float)cnt, 1.0f);
  float mp = (cnt > 0) ? mx : 0.0f;
  gvec[g * 64 + lane] = mean + mp;
}

// ---------------- MLP head ----------------
__global__ __launch_bounds__(256) void k_mlp(const float* __restrict__ gvec,
                                             const float* __restrict__ w1,
                                             const float* __restrict__ b1,
                                             const float* __restrict__ w2,
                                             const float* __restrict__ b2,
                                             float* __restrict__ out, int B) {
  int g = blockIdx.x * blockDim.x + threadIdx.x;
  if (g >= B) return;
  float gv[64];
#pragma unroll
  for (int i = 0; i < 64; i++) gv[i] = gvec[g * 64 + i];
  float o0 = b2[0], o1 = b2[1];
  for (int j = 0; j < 32; j++) {
    float a = b1[j];
#pragma unroll
    for (int i = 0; i < 64; i++) a = fmaf(gv[i], w1[i * 32 + j], a);
    a = fmaxf(a, 0.0f);
    o0 = fmaf(a, w2[j * 2 + 0], o0);
    o1 = fmaf(a, w2[j * 2 + 1], o1);
  }
  out[g * 2 + 0] = o0;
  out[g * 2 + 1] = o1;
}

// ---------------- launch ----------------
extern "C" void kernel_launch(void* const* d_in, const int* in_sizes, int n_in,
                              void* d_out, int out_size, void* d_ws, size_t ws_size,
                              hipStream_t stream) {
  const float* x     = (const float*)d_in[0];
  const int*   ei    = (const int*)d_in[1];
  const int*   batch = (const int*)d_in[2];
  const float* w0 = (const float*)d_in[3];  const float* b0 = (const float*)d_in[4];
  const float* w1 = (const float*)d_in[5];  const float* b1 = (const float*)d_in[6];
  const float* w2 = (const float*)d_in[7];  const float* b2 = (const float*)d_in[8];
  const float* gat_w = (const float*)d_in[9];
  const float* att_s = (const float*)d_in[10];
  const float* att_d = (const float*)d_in[11];
  const float* gat_b = (const float*)d_in[12];
  const float* l1w = (const float*)d_in[13]; const float* l1b = (const float*)d_in[14];
  const float* l2w = (const float*)d_in[15]; const float* l2b = (const float*)d_in[16];

  const int N = in_sizes[0] / 128;
  const int E = in_sizes[1] / 2;
  const int B = out_size / 2;

  char* ws = (char*)d_ws;
  size_t off = 0;
  auto alloc = [&](size_t bytes) -> void* {
    void* p = ws + off;
    off = (off + bytes + 255) & ~(size_t)255;
    return p;
  };
  int*   deg      = (int*)alloc((size_t)N * 4);
  int*   cursor   = (int*)alloc((size_t)N * 4);
  int*   rowstart = (int*)alloc((size_t)(N + 1) * 4);
  int*   colidx   = (int*)alloc((size_t)(E + N) * 4);
  float* dinv     = (float*)alloc((size_t)N * 4);
  float* hbuf     = (float*)alloc((size_t)N * 64 * 4);
  float* act      = (float*)alloc((size_t)N * 64 * 4);
  float* xg       = (float*)alloc((size_t)N * 64 * 4);
  float* a_src    = (float*)alloc((size_t)N * 4 * 4);
  float* a_dst    = (float*)alloc((size_t)N * 4 * 4);
  float* q_src    = (float*)alloc(4 * 64 * 4);
  float* q_dst    = (float*)alloc(4 * 64 * 4);
  int*   gs       = (int*)alloc((size_t)(B + 1) * 4);
  float* gvec     = (float*)alloc((size_t)B * 64 * 4);
  (void)ws_size; (void)n_in;

  // CSR build
  k_initdeg<<<(N + 255) / 256, 256, 0, stream>>>(deg, N);
  k_count<<<(E + 255) / 256, 256, 0, stream>>>(ei + E, deg, E);
  k_scan<<<1, 1024, 0, stream>>>(deg, rowstart, cursor, N);
  k_dinv<<<(N + 255) / 256, 256, 0, stream>>>(deg, dinv, N);
  k_scatter<<<(E + N + 255) / 256, 256, 0, stream>>>(ei, ei + E, cursor, colidx, E, N);
  k_qpre<<<1, 256, 0, stream>>>(gat_w, att_s, att_d, q_src, q_dst);

  const int AGB = 2048;  // grid-stride agg blocks
  // K1: h0 = x @ W0
  k_gemm0<<<1280, 256, 0, stream>>>(x, w0, hbuf, N);
  // K2: x1 = relu(agg(h0)+b0); h1 = x1@W1
  k_agg_gemm<<<AGB, 256, 0, stream>>>(hbuf, dinv, rowstart, colidx, b0, w1, act, N);
  // K3: x2 = relu(agg(h1)+b1); h2 = x2@W2
  k_agg_gemm<<<AGB, 256, 0, stream>>>(act, dinv, rowstart, colidx, b1, w2, hbuf, N);
  // K4: x3 = relu(agg(h2)+b2); a_src/a_dst via folded q vectors
  k_agg_gatpre<<<AGB, 256, 0, stream>>>(hbuf, dinv, rowstart, colidx, b2,
                                        q_src, q_dst, xg, a_src, a_dst, N);
  // K5: GAT aggregate + per-head GEMV + mean + bias + relu
  k_gat_agg<<<AGB, 256, 0, stream>>>(xg, gat_w, a_src, a_dst, rowstart, colidx,
                                     gat_b, act, N);
  // pooling + head
  k_gstart<<<(B + 1 + 255) / 256, 256, 0, stream>>>(batch, gs, N, B);
  k_pool<<<(B + 3) / 4, 256, 0, stream>>>(act, gs, gvec, B);
  k_mlp<<<(B + 255) / 256, 256, 0, stream>>>(gvec, l1w, l1b, l2w, l2b, (float*)d_out, B);
}

// Round 3
// 700.910 us; speedup vs baseline: 1.7875x; 1.7875x over previous
//
#include <hip/hip_runtime.h>
#include <math.h>

// ---------------- helpers ----------------
__device__ __forceinline__ float lanebcast(float v, int l) {
  return __int_as_float(__builtin_amdgcn_readlane(__float_as_int(v), l));
}

__device__ __forceinline__ float wave_sum(float v) {
#pragma unroll
  for (int off = 32; off > 0; off >>= 1) v += __shfl_xor(v, off, 64);
  return v;
}

// ---------------- CSR build ----------------
__global__ void k_initdeg(int* deg, int n) {
  int i = blockIdx.x * blockDim.x + threadIdx.x;
  if (i < n) deg[i] = 1;  // self-loop
}

__global__ void k_count(const int* __restrict__ dst, int* deg, int E) {
  int e = blockIdx.x * blockDim.x + threadIdx.x;
  if (e < E) atomicAdd(&deg[dst[e]], 1);
}

// single-block exclusive scan
__global__ void k_scan(const int* __restrict__ deg, int* rowstart, int* cursor, int n) {
  __shared__ int smem[1024];
  __shared__ int carry_s;
  int tid = threadIdx.x;
  if (tid == 0) carry_s = 0;
  __syncthreads();
  const int PER = 8;
  for (int base = 0; base < n; base += 1024 * PER) {
    int vals[PER];
    int s = 0;
#pragma unroll
    for (int p = 0; p < PER; p++) {
      int i = base + tid * PER + p;
      int v = (i < n) ? deg[i] : 0;
      vals[p] = v;
      s += v;
    }
    smem[tid] = s;
    __syncthreads();
    for (int off = 1; off < 1024; off <<= 1) {
      int t = (tid >= off) ? smem[tid - off] : 0;
      __syncthreads();
      smem[tid] += t;
      __syncthreads();
    }
    int c = carry_s;
    int excl = smem[tid] - s + c;
    __syncthreads();
    if (tid == 1023) carry_s = c + smem[1023];
#pragma unroll
    for (int p = 0; p < PER; p++) {
      int i = base + tid * PER + p;
      if (i < n) { rowstart[i] = excl; cursor[i] = excl; }
      excl += vals[p];
    }
    __syncthreads();
  }
  if (tid == 0) rowstart[n] = carry_s;
}

__global__ void k_dinv(const int* __restrict__ deg, float* dinv, int n) {
  int i = blockIdx.x * blockDim.x + threadIdx.x;
  if (i < n) dinv[i] = 1.0f / sqrtf((float)deg[i]);
}

__global__ void k_scatter(const int* __restrict__ ei_src, const int* __restrict__ ei_dst,
                          int* cursor, int* colidx, int E, int n) {
  int e = blockIdx.x * blockDim.x + threadIdx.x;
  if (e >= E + n) return;
  int s, d;
  if (e < E) { s = ei_src[e]; d = ei_dst[e]; }
  else       { s = e - E; d = s; }
  int pos = atomicAdd(&cursor[d], 1);
  colidx[pos] = s;
}

// ---------------- K1: H0'[N,64] = dinv[n] * (X[N,128] @ W0[128,64]) --------
__global__ __launch_bounds__(256) void k_gemm0(
    const float* __restrict__ A, const float* __restrict__ W,
    const float* __restrict__ dinv, float* __restrict__ H, int n) {
  __shared__ float lds_w[128 * 64];
  int tid = threadIdx.x;
  for (int idx = tid; idx < 128 * 64; idx += 256) lds_w[idx] = W[idx];
  __syncthreads();
  int wave = tid >> 6, lane = tid & 63;
  const int ROWS = 8;
  for (int rowbase = (blockIdx.x * 4 + wave) * ROWS; rowbase < n;
       rowbase += gridDim.x * 4 * ROWS) {
    float xr[ROWS][2];
#pragma unroll
    for (int r = 0; r < ROWS; r++) {
      int row = rowbase + r;
#pragma unroll
      for (int q = 0; q < 2; q++)
        xr[r][q] = (row < n) ? A[(size_t)row * 128 + q * 64 + lane] : 0.0f;
    }
    float acc[ROWS];
#pragma unroll
    for (int r = 0; r < ROWS; r++) acc[r] = 0.0f;
#pragma unroll
    for (int q = 0; q < 2; q++) {
#pragma unroll 8
      for (int kk = 0; kk < 64; kk++) {
        float wv = lds_w[(q * 64 + kk) * 64 + lane];
#pragma unroll
        for (int r = 0; r < ROWS; r++)
          acc[r] = fmaf(lanebcast(xr[r][q], kk), wv, acc[r]);
      }
    }
#pragma unroll
    for (int r = 0; r < ROWS; r++) {
      int row = rowbase + r;
      if (row < n) H[(size_t)row * 64 + lane] = acc[r] * dinv[row];
    }
  }
}

// ---------------- K2/K3: fused GCN agg + next GEMM ----------------
// h_in is pre-scaled by dinv[src]. x_next = relu(dinv_n * sum h_in[s] + b)
// h_out = dinv_n * (x_next @ Wn)   (pre-scaled for next layer's gather)
__global__ __launch_bounds__(256) void k_agg_gemm(
    const float* __restrict__ h_in, const float* __restrict__ dinv,
    const int* __restrict__ rowstart, const int* __restrict__ colidx,
    const float* __restrict__ bias, const float* __restrict__ Wn,
    float* __restrict__ h_out, int n) {
  __shared__ float lds_w[64 * 64];
  int tid = threadIdx.x;
  for (int idx = tid; idx < 64 * 64; idx += 256) lds_w[idx] = Wn[idx];
  __syncthreads();
  int lane = tid & 63;
  float bv = bias[lane];
  int gw = blockIdx.x * 4 + (tid >> 6);
  int nw = gridDim.x * 4;
  for (int node = gw; node < n; node += nw) {
    int s0 = rowstart[node], s1 = rowstart[node + 1];
    float acc = 0.0f, acc2 = 0.0f;
    int idx = s0;
    for (; idx + 1 < s1; idx += 2) {
      int sa = colidx[idx], sb = colidx[idx + 1];
      acc += h_in[(size_t)sa * 64 + lane];
      acc2 += h_in[(size_t)sb * 64 + lane];
    }
    if (idx < s1) acc += h_in[(size_t)colidx[idx] * 64 + lane];
    acc += acc2;
    float dvn = dinv[node];
    float x1 = fmaxf(fmaf(dvn, acc, bv), 0.0f);
    float o = 0.0f;
#pragma unroll 8
    for (int k = 0; k < 64; k++)
      o = fmaf(lanebcast(x1, k), lds_w[k * 64 + lane], o);
    h_out[(size_t)node * 64 + lane] = o * dvn;
  }
}

// ---------------- K4: GCN layer-2 agg + GAT attention logits ----------------
// x3 = relu(dinv_n*agg + b2) (NOT pre-scaled); a_src[n,h] = x3.q_src[h]
__global__ __launch_bounds__(256) void k_agg_gatpre(
    const float* __restrict__ h_in, const float* __restrict__ dinv,
    const int* __restrict__ rowstart, const int* __restrict__ colidx,
    const float* __restrict__ bias,
    const float* __restrict__ q_src, const float* __restrict__ q_dst,
    float* __restrict__ x3, float* __restrict__ a_src, float* __restrict__ a_dst,
    int n) {
  int tid = threadIdx.x;
  int lane = tid & 63;
  float bv = bias[lane];
  float qs[4], qd[4];
#pragma unroll
  for (int h = 0; h < 4; h++) {
    qs[h] = q_src[h * 64 + lane];
    qd[h] = q_dst[h * 64 + lane];
  }
  int gw = blockIdx.x * 4 + (tid >> 6);
  int nw = gridDim.x * 4;
  for (int node = gw; node < n; node += nw) {
    int s0 = rowstart[node], s1 = rowstart[node + 1];
    float acc = 0.0f, acc2 = 0.0f;
    int idx = s0;
    for (; idx + 1 < s1; idx += 2) {
      int sa = colidx[idx], sb = colidx[idx + 1];
      acc += h_in[(size_t)sa * 64 + lane];
      acc2 += h_in[(size_t)sb * 64 + lane];
    }
    if (idx < s1) acc += h_in[(size_t)colidx[idx] * 64 + lane];
    acc += acc2;
    float xv = fmaxf(fmaf(dinv[node], acc, bv), 0.0f);
    x3[(size_t)node * 64 + lane] = xv;
    float ps[4], pd[4];
#pragma unroll
    for (int h = 0; h < 4; h++) {
      ps[h] = wave_sum(xv * qs[h]);
      pd[h] = wave_sum(xv * qd[h]);
    }
    if (lane == 0) {
      *(float4*)&a_src[(size_t)node * 4] = make_float4(ps[0], ps[1], ps[2], ps[3]);
      *(float4*)&a_dst[(size_t)node * 4] = make_float4(pd[0], pd[1], pd[2], pd[3]);
    }
  }
}

// q[h][k] = sum_c W[k, h*64+c] * att[h][c]
__global__ void k_qpre(const float* __restrict__ W, const float* __restrict__ att_s,
                       const float* __restrict__ att_d,
                       float* __restrict__ q_src, float* __restrict__ q_dst) {
  int t = threadIdx.x;
  int h = t >> 6, k = t & 63;
  float ss = 0.0f, sd = 0.0f;
  for (int c = 0; c < 64; c++) {
    float w = W[k * 256 + h * 64 + c];
    ss = fmaf(w, att_s[h * 64 + c], ss);
    sd = fmaf(w, att_d[h * 64 + c], sd);
  }
  q_src[h * 64 + k] = ss;
  q_dst[h * 64 + k] = sd;
}

// ---------------- K5a: GAT softmax-aggregate in x-space (no projection) ----
// aggout[n, h*64+c] = (0.25/S_h) * sum_s exp(lrelu(a_src[s,h]+a_dst[n,h])) * x3[s,c]
__global__ __launch_bounds__(256) void k_gat_gather(
    const float* __restrict__ x3, const float* __restrict__ a_src,
    const float* __restrict__ a_dst, const int* __restrict__ rowstart,
    const int* __restrict__ colidx, float* __restrict__ aggout, int n) {
  int node = (blockIdx.x * blockDim.x + threadIdx.x) >> 6;
  int lane = threadIdx.x & 63;
  if (node >= n) return;
  const float4 adv = *(const float4*)&a_dst[(size_t)node * 4];
  int s0 = rowstart[node], s1 = rowstart[node + 1];
  float acc0 = 0, acc1 = 0, acc2 = 0, acc3 = 0;
  float S0 = 0, S1 = 0, S2 = 0, S3 = 0;
  for (int idx = s0; idx < s1; ++idx) {
    int s = colidx[idx];
    const float4 as = *(const float4*)&a_src[(size_t)s * 4];
    float e0 = as.x + adv.x; e0 = (e0 > 0.f) ? e0 : 0.2f * e0; float w0 = __expf(e0);
    float e1 = as.y + adv.y; e1 = (e1 > 0.f) ? e1 : 0.2f * e1; float w1 = __expf(e1);
    float e2 = as.z + adv.z; e2 = (e2 > 0.f) ? e2 : 0.2f * e2; float w2 = __expf(e2);
    float e3 = as.w + adv.w; e3 = (e3 > 0.f) ? e3 : 0.2f * e3; float w3 = __expf(e3);
    float v = x3[(size_t)s * 64 + lane];
    S0 += w0; S1 += w1; S2 += w2; S3 += w3;
    acc0 = fmaf(w0, v, acc0);
    acc1 = fmaf(w1, v, acc1);
    acc2 = fmaf(w2, v, acc2);
    acc3 = fmaf(w3, v, acc3);
  }
  size_t base = (size_t)node * 256 + lane;
  aggout[base] = acc0 * (0.25f / S0);
  aggout[base + 64] = acc1 * (0.25f / S1);
  aggout[base + 128] = acc2 * (0.25f / S2);
  aggout[base + 192] = acc3 * (0.25f / S3);
}

// ---------------- K5b: projection out = relu(agg[N,256] @ Wcat + b) --------
// Wcat[k=h*64+c][j] = gat_w[c*256 + h*64 + j]
__global__ __launch_bounds__(256) void k_gat_proj(
    const float* __restrict__ agg, const float* __restrict__ Wg,
    const float* __restrict__ bias, float* __restrict__ out, int n) {
  __shared__ float lds_w[256 * 64];  // 64 KB
  int tid = threadIdx.x;
  for (int idx = tid; idx < 256 * 64; idx += 256) {
    int k = idx >> 6, j = idx & 63;
    int h = k >> 6, c = k & 63;
    lds_w[idx] = Wg[c * 256 + h * 64 + j];
  }
  __syncthreads();
  int wave = tid >> 6, lane = tid & 63;
  float bv = bias[lane];
  const int ROWS = 8;
  for (int rowbase = (blockIdx.x * 4 + wave) * ROWS; rowbase < n;
       rowbase += gridDim.x * 4 * ROWS) {
    float xr[ROWS][4];
#pragma unroll
    for (int r = 0; r < ROWS; r++) {
      int row = rowbase + r;
#pragma unroll
      for (int q = 0; q < 4; q++)
        xr[r][q] = (row < n) ? agg[(size_t)row * 256 + q * 64 + lane] : 0.0f;
    }
    float acc[ROWS];
#pragma unroll
    for (int r = 0; r < ROWS; r++) acc[r] = 0.0f;
#pragma unroll
    for (int q = 0; q < 4; q++) {
#pragma unroll 8
      for (int kk = 0; kk < 64; kk++) {
        float wv = lds_w[(q * 64 + kk) * 64 + lane];
#pragma unroll
        for (int r = 0; r < ROWS; r++)
          acc[r] = fmaf(lanebcast(xr[r][q], kk), wv, acc[r]);
      }
    }
#pragma unroll
    for (int r = 0; r < ROWS; r++) {
      int row = rowbase + r;
      if (row < n) out[(size_t)row * 64 + lane] = fmaxf(acc[r] + bv, 0.0f);
    }
  }
}

// ---------------- pooling ----------------
__global__ void k_gstart(const int* __restrict__ batch, int* gs, int n, int B) {
  int g = blockIdx.x * blockDim.x + threadIdx.x;
  if (g > B) return;
  int lo = 0, hi = n;
  while (lo < hi) {
    int mid = (lo + hi) >> 1;
    if (batch[mid] < g) lo = mid + 1; else hi = mid;
  }
  gs[g] = lo;
}

__global__ __launch_bounds__(256) void k_pool(const float* __restrict__ x,
                                              const int* __restrict__ gs,
                                              float* __restrict__ gvec, int B) {
  int g = (blockIdx.x * blockDim.x + threadIdx.x) >> 6;
  int lane = threadIdx.x & 63;
  if (g >= B) return;
  int s0 = gs[g], s1 = gs[g + 1];
  float sum = 0.0f, mx = -INFINITY;
  for (int nd = s0; nd < s1; ++nd) {
    float v = x[(size_t)nd * 64 + lane];
    sum += v;
    mx = fmaxf(mx, v);
  }
  int cnt = s1 - s0;
  float mean = sum / fmaxf((float)cnt, 1.0f);
  float mp = (cnt > 0) ? mx : 0.0f;
  gvec[g * 64 + lane] = mean + mp;
}

// ---------------- MLP head ----------------
__global__ __launch_bounds__(256) void k_mlp(const float* __restrict__ gvec,
                                             const float* __restrict__ w1,
                                             const float* __restrict__ b1,
                                             const float* __restrict__ w2,
                                             const float* __restrict__ b2,
                                             float* __restrict__ out, int B) {
  int g = blockIdx.x * blockDim.x + threadIdx.x;
  if (g >= B) return;
  float gv[64];
#pragma unroll
  for (int i = 0; i < 64; i++) gv[i] = gvec[g * 64 + i];
  float o0 = b2[0], o1 = b2[1];
  for (int j = 0; j < 32; j++) {
    float a = b1[j];
#pragma unroll
    for (int i = 0; i < 64; i++) a = fmaf(gv[i], w1[i * 32 + j], a);
    a = fmaxf(a, 0.0f);
    o0 = fmaf(a, w2[j * 2 + 0], o0);
    o1 = fmaf(a, w2[j * 2 + 1], o1);
  }
  out[g * 2 + 0] = o0;
  out[g * 2 + 1] = o1;
}

// ---------------- launch ----------------
extern "C" void kernel_launch(void* const* d_in, const int* in_sizes, int n_in,
                              void* d_out, int out_size, void* d_ws, size_t ws_size,
                              hipStream_t stream) {
  const float* x     = (const float*)d_in[0];
  const int*   ei    = (const int*)d_in[1];
  const int*   batch = (const int*)d_in[2];
  const float* w0 = (const float*)d_in[3];  const float* b0 = (const float*)d_in[4];
  const float* w1 = (const float*)d_in[5];  const float* b1 = (const float*)d_in[6];
  const float* w2 = (const float*)d_in[7];  const float* b2 = (const float*)d_in[8];
  const float* gat_w = (const float*)d_in[9];
  const float* att_s = (const float*)d_in[10];
  const float* att_d = (const float*)d_in[11];
  const float* gat_b = (const float*)d_in[12];
  const float* l1w = (const float*)d_in[13]; const float* l1b = (const float*)d_in[14];
  const float* l2w = (const float*)d_in[15]; const float* l2b = (const float*)d_in[16];

  const int N = in_sizes[0] / 128;
  const int E = in_sizes[1] / 2;
  const int B = out_size / 2;

  char* ws = (char*)d_ws;
  size_t off = 0;
  auto alloc = [&](size_t bytes) -> void* {
    void* p = ws + off;
    off = (off + bytes + 255) & ~(size_t)255;
    return p;
  };
  int*   deg      = (int*)alloc((size_t)N * 4);
  int*   cursor   = (int*)alloc((size_t)N * 4);
  int*   rowstart = (int*)alloc((size_t)(N + 1) * 4);
  int*   colidx   = (int*)alloc((size_t)(E + N) * 4);
  float* dinv     = (float*)alloc((size_t)N * 4);
  float* hbuf     = (float*)alloc((size_t)N * 64 * 4);
  float* act      = (float*)alloc((size_t)N * 64 * 4);
  float* xg       = (float*)alloc((size_t)N * 64 * 4);
  float* aggbuf   = (float*)alloc((size_t)N * 256 * 4);
  float* a_src    = (float*)alloc((size_t)N * 4 * 4);
  float* a_dst    = (float*)alloc((size_t)N * 4 * 4);
  float* q_src    = (float*)alloc(4 * 64 * 4);
  float* q_dst    = (float*)alloc(4 * 64 * 4);
  int*   gs       = (int*)alloc((size_t)(B + 1) * 4);
  float* gvec     = (float*)alloc((size_t)B * 64 * 4);
  (void)ws_size; (void)n_in;

  // CSR build
  k_initdeg<<<(N + 255) / 256, 256, 0, stream>>>(deg, N);
  k_count<<<(E + 255) / 256, 256, 0, stream>>>(ei + E, deg, E);
  k_scan<<<1, 1024, 0, stream>>>(deg, rowstart, cursor, N);
  k_dinv<<<(N + 255) / 256, 256, 0, stream>>>(deg, dinv, N);
  k_scatter<<<(E + N + 255) / 256, 256, 0, stream>>>(ei, ei + E, cursor, colidx, E, N);
  k_qpre<<<1, 256, 0, stream>>>(gat_w, att_s, att_d, q_src, q_dst);

  const int AGB = 2048;
  // K1: h0' = dinv * (x @ W0)
  k_gemm0<<<1280, 256, 0, stream>>>(x, w0, dinv, hbuf, N);
  // K2: x1 = relu(dinv*agg(h0')+b0); h1' = dinv*(x1@W1)
  k_agg_gemm<<<AGB, 256, 0, stream>>>(hbuf, dinv, rowstart, colidx, b0, w1, act, N);
  // K3
  k_agg_gemm<<<AGB, 256, 0, stream>>>(act, dinv, rowstart, colidx, b1, w2, hbuf, N);
  // K4: x3 + attention logits
  k_agg_gatpre<<<AGB, 256, 0, stream>>>(hbuf, dinv, rowstart, colidx, b2,
                                        q_src, q_dst, xg, a_src, a_dst, N);
  // K5a: softmax-weighted gather in x-space
  k_gat_gather<<<(N + 3) / 4, 256, 0, stream>>>(xg, a_src, a_dst, rowstart, colidx,
                                                aggbuf, N);
  // K5b: projection + head-mean + bias + relu
  k_gat_proj<<<1280, 256, 0, stream>>>(aggbuf, gat_w, gat_b, act, N);
  // pooling + head
  k_gstart<<<(B + 1 + 255) / 256, 256, 0, stream>>>(batch, gs, N, B);
  k_pool<<<(B + 3) / 4, 256, 0, stream>>>(act, gs, gvec, B);
  k_mlp<<<(B + 255) / 256, 256, 0, stream>>>(gvec, l1w, l1b, l2w, l2b, (float*)d_out, B);
}

// Round 4
// 610.754 us; speedup vs baseline: 2.0513x; 1.1476x over previous
//
#include <hip/hip_runtime.h>
#include <math.h>

// ---------------- helpers ----------------
__device__ __forceinline__ float lanebcast(float v, int l) {
  return __int_as_float(__builtin_amdgcn_readlane(__float_as_int(v), l));
}
__device__ __forceinline__ int ilanebcast(int v, int l) {
  return __builtin_amdgcn_readlane(v, l);
}

__device__ __forceinline__ float wave_sum(float v) {
#pragma unroll
  for (int off = 32; off > 0; off >>= 1) v += __shfl_xor(v, off, 64);
  return v;
}

// ---------------- CSR build ----------------
__global__ void k_initdeg(int* deg, int n) {
  int i = blockIdx.x * blockDim.x + threadIdx.x;
  if (i < n) deg[i] = 1;  // self-loop
}

__global__ void k_count(const int* __restrict__ dst, int* deg, int E) {
  int e = blockIdx.x * blockDim.x + threadIdx.x;
  if (e < E) atomicAdd(&deg[dst[e]], 1);
}

// single-block exclusive scan
__global__ void k_scan(const int* __restrict__ deg, int* rowstart, int* cursor, int n) {
  __shared__ int smem[1024];
  __shared__ int carry_s;
  int tid = threadIdx.x;
  if (tid == 0) carry_s = 0;
  __syncthreads();
  const int PER = 8;
  for (int base = 0; base < n; base += 1024 * PER) {
    int vals[PER];
    int s = 0;
#pragma unroll
    for (int p = 0; p < PER; p++) {
      int i = base + tid * PER + p;
      int v = (i < n) ? deg[i] : 0;
      vals[p] = v;
      s += v;
    }
    smem[tid] = s;
    __syncthreads();
    for (int off = 1; off < 1024; off <<= 1) {
      int t = (tid >= off) ? smem[tid - off] : 0;
      __syncthreads();
      smem[tid] += t;
      __syncthreads();
    }
    int c = carry_s;
    int excl = smem[tid] - s + c;
    __syncthreads();
    if (tid == 1023) carry_s = c + smem[1023];
#pragma unroll
    for (int p = 0; p < PER; p++) {
      int i = base + tid * PER + p;
      if (i < n) { rowstart[i] = excl; cursor[i] = excl; }
      excl += vals[p];
    }
    __syncthreads();
  }
  if (tid == 0) rowstart[n] = carry_s;
}

__global__ void k_dinv(const int* __restrict__ deg, float* dinv, int n) {
  int i = blockIdx.x * blockDim.x + threadIdx.x;
  if (i < n) dinv[i] = 1.0f / sqrtf((float)deg[i]);
}

__global__ void k_scatter(const int* __restrict__ ei_src, const int* __restrict__ ei_dst,
                          int* cursor, int* colidx, int E, int n) {
  int e = blockIdx.x * blockDim.x + threadIdx.x;
  if (e >= E + n) return;
  int s, d;
  if (e < E) { s = ei_src[e]; d = ei_dst[e]; }
  else       { s = e - E; d = s; }
  int pos = atomicAdd(&cursor[d], 1);
  colidx[pos] = s;
}

// ---------------- K1: H0'[N,64] = dinv[n] * (X[N,128] @ W0[128,64]) --------
__global__ __launch_bounds__(256) void k_gemm0(
    const float* __restrict__ A, const float* __restrict__ W,
    const float* __restrict__ dinv, float* __restrict__ H, int n) {
  __shared__ float lds_w[128 * 64];
  int tid = threadIdx.x;
  for (int idx = tid; idx < 128 * 64; idx += 256) lds_w[idx] = W[idx];
  __syncthreads();
  int wave = tid >> 6, lane = tid & 63;
  const int ROWS = 8;
  for (int rowbase = (blockIdx.x * 4 + wave) * ROWS; rowbase < n;
       rowbase += gridDim.x * 4 * ROWS) {
    float xr[ROWS][2];
#pragma unroll
    for (int r = 0; r < ROWS; r++) {
      int row = rowbase + r;
#pragma unroll
      for (int q = 0; q < 2; q++)
        xr[r][q] = (row < n) ? A[(size_t)row * 128 + q * 64 + lane] : 0.0f;
    }
    float acc[ROWS];
#pragma unroll
    for (int r = 0; r < ROWS; r++) acc[r] = 0.0f;
#pragma unroll
    for (int q = 0; q < 2; q++) {
#pragma unroll 8
      for (int kk = 0; kk < 64; kk++) {
        float wv = lds_w[(q * 64 + kk) * 64 + lane];
#pragma unroll
        for (int r = 0; r < ROWS; r++)
          acc[r] = fmaf(lanebcast(xr[r][q], kk), wv, acc[r]);
      }
    }
#pragma unroll
    for (int r = 0; r < ROWS; r++) {
      int row = rowbase + r;
      if (row < n) H[(size_t)row * 64 + lane] = acc[r] * dinv[row];
    }
  }
}

// ---------------- gather core: sum of h_in rows listed in colidx[s0:s1) -----
// batched index load (one coalesced load per 64 edges) + readlane broadcast so
// each edge's gather is SGPR-base + lane*4 with no dependent-load chain.
__device__ __forceinline__ float gather_sum(const float* __restrict__ h_in,
                                            const int* __restrict__ colidx,
                                            int s0, int s1, int lane) {
  float acc = 0.0f, accB = 0.0f;
  for (int base = s0; base < s1; base += 64) {
    int cnt = min(64, s1 - base);
    int myidx = (lane < cnt) ? colidx[base + lane] : 0;
    int k = 0;
    for (; k + 3 < cnt; k += 4) {
      int sa = ilanebcast(myidx, k);
      int sb = ilanebcast(myidx, k + 1);
      int sc = ilanebcast(myidx, k + 2);
      int sd = ilanebcast(myidx, k + 3);
      float va = h_in[(size_t)sa * 64 + lane];
      float vb = h_in[(size_t)sb * 64 + lane];
      float vc = h_in[(size_t)sc * 64 + lane];
      float vd = h_in[(size_t)sd * 64 + lane];
      acc += va; accB += vb; acc += vc; accB += vd;
    }
    for (; k < cnt; k++) {
      int sa = ilanebcast(myidx, k);
      acc += h_in[(size_t)sa * 64 + lane];
    }
  }
  return acc + accB;
}

// ---------------- K2/K3: fused GCN agg + next GEMM ----------------
__global__ __launch_bounds__(256) void k_agg_gemm(
    const float* __restrict__ h_in, const float* __restrict__ dinv,
    const int* __restrict__ rowstart, const int* __restrict__ colidx,
    const float* __restrict__ bias, const float* __restrict__ Wn,
    float* __restrict__ h_out, int n) {
  __shared__ float lds_w[64 * 64];
  int tid = threadIdx.x;
  for (int idx = tid; idx < 64 * 64; idx += 256) lds_w[idx] = Wn[idx];
  __syncthreads();
  int lane = tid & 63;
  float bv = bias[lane];
  int gw = blockIdx.x * 4 + (tid >> 6);
  int nw = gridDim.x * 4;
  for (int node = gw; node < n; node += nw) {
    int s0 = rowstart[node], s1 = rowstart[node + 1];
    float acc = gather_sum(h_in, colidx, s0, s1, lane);
    float dvn = dinv[node];
    float x1 = fmaxf(fmaf(dvn, acc, bv), 0.0f);
    float o = 0.0f;
#pragma unroll 8
    for (int k = 0; k < 64; k++)
      o = fmaf(lanebcast(x1, k), lds_w[k * 64 + lane], o);
    h_out[(size_t)node * 64 + lane] = o * dvn;
  }
}

// ---------------- K4: GCN layer-2 agg + GAT attention logits ----------------
__global__ __launch_bounds__(256) void k_agg_gatpre(
    const float* __restrict__ h_in, const float* __restrict__ dinv,
    const int* __restrict__ rowstart, const int* __restrict__ colidx,
    const float* __restrict__ bias,
    const float* __restrict__ q_src, const float* __restrict__ q_dst,
    float* __restrict__ x3, float* __restrict__ a_src, float* __restrict__ a_dst,
    int n) {
  int tid = threadIdx.x;
  int lane = tid & 63;
  float bv = bias[lane];
  float qs[4], qd[4];
#pragma unroll
  for (int h = 0; h < 4; h++) {
    qs[h] = q_src[h * 64 + lane];
    qd[h] = q_dst[h * 64 + lane];
  }
  int gw = blockIdx.x * 4 + (tid >> 6);
  int nw = gridDim.x * 4;
  for (int node = gw; node < n; node += nw) {
    int s0 = rowstart[node], s1 = rowstart[node + 1];
    float acc = gather_sum(h_in, colidx, s0, s1, lane);
    float xv = fmaxf(fmaf(dinv[node], acc, bv), 0.0f);
    x3[(size_t)node * 64 + lane] = xv;
    float ps[4], pd[4];
#pragma unroll
    for (int h = 0; h < 4; h++) {
      ps[h] = wave_sum(xv * qs[h]);
      pd[h] = wave_sum(xv * qd[h]);
    }
    if (lane == 0) {
      *(float4*)&a_src[(size_t)node * 4] = make_float4(ps[0], ps[1], ps[2], ps[3]);
      *(float4*)&a_dst[(size_t)node * 4] = make_float4(pd[0], pd[1], pd[2], pd[3]);
    }
  }
}

// q[h][k] = sum_c W[k, h*64+c] * att[h][c]
__global__ void k_qpre(const float* __restrict__ W, const float* __restrict__ att_s,
                       const float* __restrict__ att_d,
                       float* __restrict__ q_src, float* __restrict__ q_dst) {
  int t = threadIdx.x;
  int h = t >> 6, k = t & 63;
  float ss = 0.0f, sd = 0.0f;
  for (int c = 0; c < 64; c++) {
    float w = W[k * 256 + h * 64 + c];
    ss = fmaf(w, att_s[h * 64 + c], ss);
    sd = fmaf(w, att_d[h * 64 + c], sd);
  }
  q_src[h * 64 + k] = ss;
  q_dst[h * 64 + k] = sd;
}

// ---------------- K5a: GAT softmax-aggregate in x-space ----------
// Weight phase is lane-parallel (lane = edge slot): the 4 exp/lrelu per edge
// are computed once, not 64x redundantly. Accumulation phase broadcasts
// idx + 4 weights via readlane; gather is SGPR-base + lane*4.
__global__ __launch_bounds__(256) void k_gat_gather(
    const float* __restrict__ x3, const float* __restrict__ a_src,
    const float* __restrict__ a_dst, const int* __restrict__ rowstart,
    const int* __restrict__ colidx, float* __restrict__ aggout, int n) {
  int node = (blockIdx.x * blockDim.x + threadIdx.x) >> 6;
  int lane = threadIdx.x & 63;
  if (node >= n) return;
  const float4 adv = *(const float4*)&a_dst[(size_t)node * 4];
  int s0 = rowstart[node], s1 = rowstart[node + 1];
  float acc0 = 0, acc1 = 0, acc2 = 0, acc3 = 0;
  float S0 = 0, S1 = 0, S2 = 0, S3 = 0;
  for (int base = s0; base < s1; base += 64) {
    int cnt = min(64, s1 - base);
    bool act = (lane < cnt);
    int myidx = act ? colidx[base + lane] : 0;
    float w0 = 0, w1 = 0, w2 = 0, w3 = 0;
    if (act) {
      const float4 as = *(const float4*)&a_src[(size_t)myidx * 4];
      float e0 = as.x + adv.x; e0 = (e0 > 0.f) ? e0 : 0.2f * e0; w0 = __expf(e0);
      float e1 = as.y + adv.y; e1 = (e1 > 0.f) ? e1 : 0.2f * e1; w1 = __expf(e1);
      float e2 = as.z + adv.z; e2 = (e2 > 0.f) ? e2 : 0.2f * e2; w2 = __expf(e2);
      float e3 = as.w + adv.w; e3 = (e3 > 0.f) ? e3 : 0.2f * e3; w3 = __expf(e3);
    }
    S0 += wave_sum(w0); S1 += wave_sum(w1);
    S2 += wave_sum(w2); S3 += wave_sum(w3);
    int k = 0;
    for (; k + 1 < cnt; k += 2) {
      int sa = ilanebcast(myidx, k);
      int sb = ilanebcast(myidx, k + 1);
      float wa0 = lanebcast(w0, k), wb0 = lanebcast(w0, k + 1);
      float wa1 = lanebcast(w1, k), wb1 = lanebcast(w1, k + 1);
      float wa2 = lanebcast(w2, k), wb2 = lanebcast(w2, k + 1);
      float wa3 = lanebcast(w3, k), wb3 = lanebcast(w3, k + 1);
      float va = x3[(size_t)sa * 64 + lane];
      float vb = x3[(size_t)sb * 64 + lane];
      acc0 = fmaf(wa0, va, acc0); acc1 = fmaf(wa1, va, acc1);
      acc2 = fmaf(wa2, va, acc2); acc3 = fmaf(wa3, va, acc3);
      acc0 = fmaf(wb0, vb, acc0); acc1 = fmaf(wb1, vb, acc1);
      acc2 = fmaf(wb2, vb, acc2); acc3 = fmaf(wb3, vb, acc3);
    }
    if (k < cnt) {
      int sa = ilanebcast(myidx, k);
      float wa0 = lanebcast(w0, k), wa1 = lanebcast(w1, k);
      float wa2 = lanebcast(w2, k), wa3 = lanebcast(w3, k);
      float va = x3[(size_t)sa * 64 + lane];
      acc0 = fmaf(wa0, va, acc0); acc1 = fmaf(wa1, va, acc1);
      acc2 = fmaf(wa2, va, acc2); acc3 = fmaf(wa3, va, acc3);
    }
  }
  size_t baseo = (size_t)node * 256 + lane;
  aggout[baseo] = acc0 * (0.25f / S0);
  aggout[baseo + 64] = acc1 * (0.25f / S1);
  aggout[baseo + 128] = acc2 * (0.25f / S2);
  aggout[baseo + 192] = acc3 * (0.25f / S3);
}

// ---------------- K5b: projection out = relu(agg[N,256] @ Wcat + b) --------
__global__ __launch_bounds__(256) void k_gat_proj(
    const float* __restrict__ agg, const float* __restrict__ Wg,
    const float* __restrict__ bias, float* __restrict__ out, int n) {
  __shared__ float lds_w[256 * 64];  // 64 KB
  int tid = threadIdx.x;
  for (int idx = tid; idx < 256 * 64; idx += 256) {
    int k = idx >> 6, j = idx & 63;
    int h = k >> 6, c = k & 63;
    lds_w[idx] = Wg[c * 256 + h * 64 + j];
  }
  __syncthreads();
  int wave = tid >> 6, lane = tid & 63;
  float bv = bias[lane];
  const int ROWS = 8;
  for (int rowbase = (blockIdx.x * 4 + wave) * ROWS; rowbase < n;
       rowbase += gridDim.x * 4 * ROWS) {
    float xr[ROWS][4];
#pragma unroll
    for (int r = 0; r < ROWS; r++) {
      int row = rowbase + r;
#pragma unroll
      for (int q = 0; q < 4; q++)
        xr[r][q] = (row < n) ? agg[(size_t)row * 256 + q * 64 + lane] : 0.0f;
    }
    float acc[ROWS];
#pragma unroll
    for (int r = 0; r < ROWS; r++) acc[r] = 0.0f;
#pragma unroll
    for (int q = 0; q < 4; q++) {
#pragma unroll 8
      for (int kk = 0; kk < 64; kk++) {
        float wv = lds_w[(q * 64 + kk) * 64 + lane];
#pragma unroll
        for (int r = 0; r < ROWS; r++)
          acc[r] = fmaf(lanebcast(xr[r][q], kk), wv, acc[r]);
      }
    }
#pragma unroll
    for (int r = 0; r < ROWS; r++) {
      int row = rowbase + r;
      if (row < n) out[(size_t)row * 64 + lane] = fmaxf(acc[r] + bv, 0.0f);
    }
  }
}

// ---------------- pooling ----------------
__global__ void k_gstart(const int* __restrict__ batch, int* gs, int n, int B) {
  int g = blockIdx.x * blockDim.x + threadIdx.x;
  if (g > B) return;
  int lo = 0, hi = n;
  while (lo < hi) {
    int mid = (lo + hi) >> 1;
    if (batch[mid] < g) lo = mid + 1; else hi = mid;
  }
  gs[g] = lo;
}

__global__ __launch_bounds__(256) void k_pool(const float* __restrict__ x,
                                              const int* __restrict__ gs,
                                              float* __restrict__ gvec, int B) {
  int g = (blockIdx.x * blockDim.x + threadIdx.x) >> 6;
  int lane = threadIdx.x & 63;
  if (g >= B) return;
  int s0 = gs[g], s1 = gs[g + 1];
  float sum = 0.0f, mx = -INFINITY;
  for (int nd = s0; nd < s1; ++nd) {
    float v = x[(size_t)nd * 64 + lane];
    sum += v;
    mx = fmaxf(mx, v);
  }
  int cnt = s1 - s0;
  float mean = sum / fmaxf((float)cnt, 1.0f);
  float mp = (cnt > 0) ? mx : 0.0f;
  gvec[g * 64 + lane] = mean + mp;
}

// ---------------- MLP head ----------------
__global__ __launch_bounds__(256) void k_mlp(const float* __restrict__ gvec,
                                             const float* __restrict__ w1,
                                             const float* __restrict__ b1,
                                             const float* __restrict__ w2,
                                             const float* __restrict__ b2,
                                             float* __restrict__ out, int B) {
  int g = blockIdx.x * blockDim.x + threadIdx.x;
  if (g >= B) return;
  float gv[64];
#pragma unroll
  for (int i = 0; i < 64; i++) gv[i] = gvec[g * 64 + i];
  float o0 = b2[0], o1 = b2[1];
  for (int j = 0; j < 32; j++) {
    float a = b1[j];
#pragma unroll
    for (int i = 0; i < 64; i++) a = fmaf(gv[i], w1[i * 32 + j], a);
    a = fmaxf(a, 0.0f);
    o0 = fmaf(a, w2[j * 2 + 0], o0);
    o1 = fmaf(a, w2[j * 2 + 1], o1);
  }
  out[g * 2 + 0] = o0;
  out[g * 2 + 1] = o1;
}

// ---------------- launch ----------------
extern "C" void kernel_launch(void* const* d_in, const int* in_sizes, int n_in,
                              void* d_out, int out_size, void* d_ws, size_t ws_size,
                              hipStream_t stream) {
  const float* x     = (const float*)d_in[0];
  const int*   ei    = (const int*)d_in[1];
  const int*   batch = (const int*)d_in[2];
  const float* w0 = (const float*)d_in[3];  const float* b0 = (const float*)d_in[4];
  const float* w1 = (const float*)d_in[5];  const float* b1 = (const float*)d_in[6];
  const float* w2 = (const float*)d_in[7];  const float* b2 = (const float*)d_in[8];
  const float* gat_w = (const float*)d_in[9];
  const float* att_s = (const float*)d_in[10];
  const float* att_d = (const float*)d_in[11];
  const float* gat_b = (const float*)d_in[12];
  const float* l1w = (const float*)d_in[13]; const float* l1b = (const float*)d_in[14];
  const float* l2w = (const float*)d_in[15]; const float* l2b = (const float*)d_in[16];

  const int N = in_sizes[0] / 128;
  const int E = in_sizes[1] / 2;
  const int B = out_size / 2;

  char* ws = (char*)d_ws;
  size_t off = 0;
  auto alloc = [&](size_t bytes) -> void* {
    void* p = ws + off;
    off = (off + bytes + 255) & ~(size_t)255;
    return p;
  };
  int*   deg      = (int*)alloc((size_t)N * 4);
  int*   cursor   = (int*)alloc((size_t)N * 4);
  int*   rowstart = (int*)alloc((size_t)(N + 1) * 4);
  int*   colidx   = (int*)alloc((size_t)(E + N) * 4);
  float* dinv     = (float*)alloc((size_t)N * 4);
  float* hbuf     = (float*)alloc((size_t)N * 64 * 4);
  float* act      = (float*)alloc((size_t)N * 64 * 4);
  float* xg       = (float*)alloc((size_t)N * 64 * 4);
  float* aggbuf   = (float*)alloc((size_t)N * 256 * 4);
  float* a_src    = (float*)alloc((size_t)N * 4 * 4);
  float* a_dst    = (float*)alloc((size_t)N * 4 * 4);
  float* q_src    = (float*)alloc(4 * 64 * 4);
  float* q_dst    = (float*)alloc(4 * 64 * 4);
  int*   gs       = (int*)alloc((size_t)(B + 1) * 4);
  float* gvec     = (float*)alloc((size_t)B * 64 * 4);
  (void)ws_size; (void)n_in;

  // CSR build
  k_initdeg<<<(N + 255) / 256, 256, 0, stream>>>(deg, N);
  k_count<<<(E + 255) / 256, 256, 0, stream>>>(ei + E, deg, E);
  k_scan<<<1, 1024, 0, stream>>>(deg, rowstart, cursor, N);
  k_dinv<<<(N + 255) / 256, 256, 0, stream>>>(deg, dinv, N);
  k_scatter<<<(E + N + 255) / 256, 256, 0, stream>>>(ei, ei + E, cursor, colidx, E, N);
  k_qpre<<<1, 256, 0, stream>>>(gat_w, att_s, att_d, q_src, q_dst);

  const int AGB = 2048;
  // K1: h0' = dinv * (x @ W0)
  k_gemm0<<<1280, 256, 0, stream>>>(x, w0, dinv, hbuf, N);
  // K2: x1 = relu(dinv*agg(h0')+b0); h1' = dinv*(x1@W1)
  k_agg_gemm<<<AGB, 256, 0, stream>>>(hbuf, dinv, rowstart, colidx, b0, w1, act, N);
  // K3
  k_agg_gemm<<<AGB, 256, 0, stream>>>(act, dinv, rowstart, colidx, b1, w2, hbuf, N);
  // K4: x3 + attention logits
  k_agg_gatpre<<<AGB, 256, 0, stream>>>(hbuf, dinv, rowstart, colidx, b2,
                                        q_src, q_dst, xg, a_src, a_dst, N);
  // K5a: softmax-weighted gather in x-space
  k_gat_gather<<<(N + 3) / 4, 256, 0, stream>>>(xg, a_src, a_dst, rowstart, colidx,
                                                aggbuf, N);
  // K5b: projection + head-mean + bias + relu
  k_gat_proj<<<1280, 256, 0, stream>>>(aggbuf, gat_w, gat_b, act, N);
  // pooling + head
  k_gstart<<<(B + 1 + 255) / 256, 256, 0, stream>>>(batch, gs, N, B);
  k_pool<<<(B + 3) / 4, 256, 0, stream>>>(act, gs, gvec, B);
  k_mlp<<<(B + 255) / 256, 256, 0, stream>>>(gvec, l1w, l1b, l2w, l2b, (float*)d_out, B);
}

// Round 5
// 536.262 us; speedup vs baseline: 2.3363x; 1.1389x over previous
//
#include <hip/hip_runtime.h>
#include <math.h>

typedef short bf8 __attribute__((ext_vector_type(8)));   // 8 bf16 in 4 VGPRs
typedef float f4 __attribute__((ext_vector_type(4)));
typedef unsigned short ushort_t;

// ---------------- helpers ----------------
__device__ __forceinline__ float lanebcast(float v, int l) {
  return __int_as_float(__builtin_amdgcn_readlane(__float_as_int(v), l));
}
__device__ __forceinline__ int ilanebcast(int v, int l) {
  return __builtin_amdgcn_readlane(v, l);
}

__device__ __forceinline__ float wave_sum(float v) {
#pragma unroll
  for (int off = 32; off > 0; off >>= 1) v += __shfl_xor(v, off, 64);
  return v;
}

__device__ __forceinline__ ushort_t f2bf(float x) {  // RNE fp32->bf16 bits
  unsigned int u = __float_as_uint(x);
  return (ushort_t)((u + 0x7fffu + ((u >> 16) & 1u)) >> 16);
}
__device__ __forceinline__ float b2f(ushort_t h) {
  return __uint_as_float(((unsigned int)h) << 16);
}

// ---------------- CSR build ----------------
__global__ void k_initdeg(int* deg, int n) {
  int i = blockIdx.x * blockDim.x + threadIdx.x;
  if (i < n) deg[i] = 1;  // self-loop
}

__global__ void k_count(const int* __restrict__ dst, int* deg, int E) {
  int e = blockIdx.x * blockDim.x + threadIdx.x;
  if (e < E) atomicAdd(&deg[dst[e]], 1);
}

__global__ void k_scan(const int* __restrict__ deg, int* rowstart, int* cursor, int n) {
  __shared__ int smem[1024];
  __shared__ int carry_s;
  int tid = threadIdx.x;
  if (tid == 0) carry_s = 0;
  __syncthreads();
  const int PER = 8;
  for (int base = 0; base < n; base += 1024 * PER) {
    int vals[PER];
    int s = 0;
#pragma unroll
    for (int p = 0; p < PER; p++) {
      int i = base + tid * PER + p;
      int v = (i < n) ? deg[i] : 0;
      vals[p] = v;
      s += v;
    }
    smem[tid] = s;
    __syncthreads();
    for (int off = 1; off < 1024; off <<= 1) {
      int t = (tid >= off) ? smem[tid - off] : 0;
      __syncthreads();
      smem[tid] += t;
      __syncthreads();
    }
    int c = carry_s;
    int excl = smem[tid] - s + c;
    __syncthreads();
    if (tid == 1023) carry_s = c + smem[1023];
#pragma unroll
    for (int p = 0; p < PER; p++) {
      int i = base + tid * PER + p;
      if (i < n) { rowstart[i] = excl; cursor[i] = excl; }
      excl += vals[p];
    }
    __syncthreads();
  }
  if (tid == 0) rowstart[n] = carry_s;
}

__global__ void k_dinv(const int* __restrict__ deg, float* dinv, int n) {
  int i = blockIdx.x * blockDim.x + threadIdx.x;
  if (i < n) dinv[i] = 1.0f / sqrtf((float)deg[i]);
}

__global__ void k_scatter(const int* __restrict__ ei_src, const int* __restrict__ ei_dst,
                          int* cursor, int* colidx, int E, int n) {
  int e = blockIdx.x * blockDim.x + threadIdx.x;
  if (e >= E + n) return;
  int s, d;
  if (e < E) { s = ei_src[e]; d = ei_dst[e]; }
  else       { s = e - E; d = s; }
  int pos = atomicAdd(&cursor[d], 1);
  colidx[pos] = s;
}

// ---------------- weight swizzle into MFMA B-fragment layout ----------------
// B-frag for 16x16x32: lane holds B[k=(lane>>4)*8+j][n=lane&15], j=0..7.
// Buffer layout: frag[( (ct*KC + kc)*64 + lane )*8 + j], hi/lo bf16 planes.

// W0 [128,64] direct
__global__ void k_wswz0(const float* __restrict__ W, ushort_t* __restrict__ Bh,
                        ushort_t* __restrict__ Bl) {
  for (int e = threadIdx.x; e < 4 * 4 * 64; e += 256) {
    int lane = e & 63, kc = (e >> 6) & 3, ct = e >> 8;
    int k0 = kc * 32 + (lane >> 4) * 8;
    int col = ct * 16 + (lane & 15);
#pragma unroll
    for (int j = 0; j < 8; j++) {
      float w = W[(k0 + j) * 64 + col];
      ushort_t h = f2bf(w);
      Bh[(size_t)e * 8 + j] = h;
      Bl[(size_t)e * 8 + j] = f2bf(w - b2f(h));
    }
  }
}

// Wg_cat [256,64]: Wcat[k=h*64+c][col] = gat_w[c*256 + h*64 + col]
__global__ void k_wswzg(const float* __restrict__ W, ushort_t* __restrict__ Bh,
                        ushort_t* __restrict__ Bl) {
  for (int e = threadIdx.x; e < 4 * 8 * 64; e += 256) {
    int lane = e & 63, kc = (e >> 6) & 7, ct = e >> 9;
    int k0 = kc * 32 + (lane >> 4) * 8;
    int col = ct * 16 + (lane & 15);
#pragma unroll
    for (int j = 0; j < 8; j++) {
      int k = k0 + j;
      float w = W[(k & 63) * 256 + (k >> 6) * 64 + col];
      ushort_t h = f2bf(w);
      Bh[(size_t)e * 8 + j] = h;
      Bl[(size_t)e * 8 + j] = f2bf(w - b2f(h));
    }
  }
}

// ---------------- K1: H0'[N,64] = dinv[n] * (X[N,128] @ W0) via MFMA -------
// 3-term compensated bf16: Ah*Bh + Al*Bh + Ah*Bl (~fp32 accuracy).
__global__ __launch_bounds__(256) void k_gemm0_mfma(
    const float* __restrict__ X, const ushort_t* __restrict__ Bh,
    const ushort_t* __restrict__ Bl, const float* __restrict__ dinv,
    float* __restrict__ H, int n, int ntiles) {
  int tid = threadIdx.x, lane = tid & 63, wave = tid >> 6;
  int m = lane & 15, q = lane >> 4;
  for (int tile = blockIdx.x * 4 + wave; tile < ntiles; tile += gridDim.x * 4) {
    int ra = tile * 16 + m;
    if (ra >= n) ra = n - 1;
    const float* xrow = X + (size_t)ra * 128;
    f4 acc[4];
#pragma unroll
    for (int ct = 0; ct < 4; ct++) acc[ct] = (f4){0.f, 0.f, 0.f, 0.f};
#pragma unroll 2
    for (int kc = 0; kc < 4; kc++) {
      int ko = kc * 32 + q * 8;
      float4 xa = *(const float4*)(xrow + ko);
      float4 xb = *(const float4*)(xrow + ko + 4);
      float f[8] = {xa.x, xa.y, xa.z, xa.w, xb.x, xb.y, xb.z, xb.w};
      union { ushort_t u[8]; bf8 v; } Uh, Ul;
#pragma unroll
      for (int j = 0; j < 8; j++) {
        ushort_t h = f2bf(f[j]);
        Uh.u[j] = h;
        Ul.u[j] = f2bf(f[j] - b2f(h));
      }
#pragma unroll
      for (int ct = 0; ct < 4; ct++) {
        size_t boff = ((size_t)(ct * 4 + kc) * 64 + lane) * 8;
        bf8 bh = *(const bf8*)(Bh + boff);
        bf8 bl = *(const bf8*)(Bl + boff);
        acc[ct] = __builtin_amdgcn_mfma_f32_16x16x32_bf16(Uh.v, bh, acc[ct], 0, 0, 0);
        acc[ct] = __builtin_amdgcn_mfma_f32_16x16x32_bf16(Ul.v, bh, acc[ct], 0, 0, 0);
        acc[ct] = __builtin_amdgcn_mfma_f32_16x16x32_bf16(Uh.v, bl, acc[ct], 0, 0, 0);
      }
    }
#pragma unroll
    for (int r = 0; r < 4; r++) {
      int row = tile * 16 + q * 4 + r;
      if (row < n) {
        float dv = dinv[row];
#pragma unroll
        for (int ct = 0; ct < 4; ct++)
          H[(size_t)row * 64 + ct * 16 + m] = acc[ct][r] * dv;
      }
    }
  }
}

// ---------------- gather core ----------------
__device__ __forceinline__ float gather_sum(const float* __restrict__ h_in,
                                            const int* __restrict__ colidx,
                                            int s0, int s1, int lane) {
  float acc = 0.0f, accB = 0.0f;
  for (int base = s0; base < s1; base += 64) {
    int cnt = min(64, s1 - base);
    int myidx = (lane < cnt) ? colidx[base + lane] : 0;
    int k = 0;
    for (; k + 3 < cnt; k += 4) {
      int sa = ilanebcast(myidx, k);
      int sb = ilanebcast(myidx, k + 1);
      int sc = ilanebcast(myidx, k + 2);
      int sd = ilanebcast(myidx, k + 3);
      float va = h_in[(size_t)sa * 64 + lane];
      float vb = h_in[(size_t)sb * 64 + lane];
      float vc = h_in[(size_t)sc * 64 + lane];
      float vd = h_in[(size_t)sd * 64 + lane];
      acc += va; accB += vb; acc += vc; accB += vd;
    }
    for (; k < cnt; k++) {
      int sa = ilanebcast(myidx, k);
      acc += h_in[(size_t)sa * 64 + lane];
    }
  }
  return acc + accB;
}

// ---------------- K2/K3: fused GCN agg + next GEMM (readlane GEMV) --------
__global__ __launch_bounds__(256) void k_agg_gemm(
    const float* __restrict__ h_in, const float* __restrict__ dinv,
    const int* __restrict__ rowstart, const int* __restrict__ colidx,
    const float* __restrict__ bias, const float* __restrict__ Wn,
    float* __restrict__ h_out, int n) {
  __shared__ float lds_w[64 * 64];
  int tid = threadIdx.x;
  for (int idx = tid; idx < 64 * 64; idx += 256) lds_w[idx] = Wn[idx];
  __syncthreads();
  int lane = tid & 63;
  float bv = bias[lane];
  int gw = blockIdx.x * 4 + (tid >> 6);
  int nw = gridDim.x * 4;
  for (int node = gw; node < n; node += nw) {
    int s0 = rowstart[node], s1 = rowstart[node + 1];
    float acc = gather_sum(h_in, colidx, s0, s1, lane);
    float dvn = dinv[node];
    float x1 = fmaxf(fmaf(dvn, acc, bv), 0.0f);
    float o = 0.0f;
#pragma unroll 8
    for (int k = 0; k < 64; k++)
      o = fmaf(lanebcast(x1, k), lds_w[k * 64 + lane], o);
    h_out[(size_t)node * 64 + lane] = o * dvn;
  }
}

// ---------------- K4: GCN layer-2 agg + GAT attention logits ----------------
__global__ __launch_bounds__(256) void k_agg_gatpre(
    const float* __restrict__ h_in, const float* __restrict__ dinv,
    const int* __restrict__ rowstart, const int* __restrict__ colidx,
    const float* __restrict__ bias,
    const float* __restrict__ q_src, const float* __restrict__ q_dst,
    float* __restrict__ x3, float* __restrict__ a_src, float* __restrict__ a_dst,
    int n) {
  int tid = threadIdx.x;
  int lane = tid & 63;
  float bv = bias[lane];
  float qs[4], qd[4];
#pragma unroll
  for (int h = 0; h < 4; h++) {
    qs[h] = q_src[h * 64 + lane];
    qd[h] = q_dst[h * 64 + lane];
  }
  int gw = blockIdx.x * 4 + (tid >> 6);
  int nw = gridDim.x * 4;
  for (int node = gw; node < n; node += nw) {
    int s0 = rowstart[node], s1 = rowstart[node + 1];
    float acc = gather_sum(h_in, colidx, s0, s1, lane);
    float xv = fmaxf(fmaf(dinv[node], acc, bv), 0.0f);
    x3[(size_t)node * 64 + lane] = xv;
    float ps[4], pd[4];
#pragma unroll
    for (int h = 0; h < 4; h++) {
      ps[h] = wave_sum(xv * qs[h]);
      pd[h] = wave_sum(xv * qd[h]);
    }
    if (lane == 0) {
      *(float4*)&a_src[(size_t)node * 4] = make_float4(ps[0], ps[1], ps[2], ps[3]);
      *(float4*)&a_dst[(size_t)node * 4] = make_float4(pd[0], pd[1], pd[2], pd[3]);
    }
  }
}

// q[h][k] = sum_c W[k, h*64+c] * att[h][c]
__global__ void k_qpre(const float* __restrict__ W, const float* __restrict__ att_s,
                       const float* __restrict__ att_d,
                       float* __restrict__ q_src, float* __restrict__ q_dst) {
  int t = threadIdx.x;
  int h = t >> 6, k = t & 63;
  float ss = 0.0f, sd = 0.0f;
  for (int c = 0; c < 64; c++) {
    float w = W[k * 256 + h * 64 + c];
    ss = fmaf(w, att_s[h * 64 + c], ss);
    sd = fmaf(w, att_d[h * 64 + c], sd);
  }
  q_src[h * 64 + k] = ss;
  q_dst[h * 64 + k] = sd;
}

// ---------------- K5a: GAT softmax-aggregate in x-space ----------
// Emits the aggregate as bf16 hi/lo planes (frag-ready for the MFMA proj).
__global__ __launch_bounds__(256) void k_gat_gather(
    const float* __restrict__ x3, const float* __restrict__ a_src,
    const float* __restrict__ a_dst, const int* __restrict__ rowstart,
    const int* __restrict__ colidx, ushort_t* __restrict__ Ahi,
    ushort_t* __restrict__ Alo, int n) {
  int node = (blockIdx.x * blockDim.x + threadIdx.x) >> 6;
  int lane = threadIdx.x & 63;
  if (node >= n) return;
  const float4 adv = *(const float4*)&a_dst[(size_t)node * 4];
  int s0 = rowstart[node], s1 = rowstart[node + 1];
  float acc0 = 0, acc1 = 0, acc2 = 0, acc3 = 0;
  float S0 = 0, S1 = 0, S2 = 0, S3 = 0;
  for (int base = s0; base < s1; base += 64) {
    int cnt = min(64, s1 - base);
    bool act = (lane < cnt);
    int myidx = act ? colidx[base + lane] : 0;
    float w0 = 0, w1 = 0, w2 = 0, w3 = 0;
    if (act) {
      const float4 as = *(const float4*)&a_src[(size_t)myidx * 4];
      float e0 = as.x + adv.x; e0 = (e0 > 0.f) ? e0 : 0.2f * e0; w0 = __expf(e0);
      float e1 = as.y + adv.y; e1 = (e1 > 0.f) ? e1 : 0.2f * e1; w1 = __expf(e1);
      float e2 = as.z + adv.z; e2 = (e2 > 0.f) ? e2 : 0.2f * e2; w2 = __expf(e2);
      float e3 = as.w + adv.w; e3 = (e3 > 0.f) ? e3 : 0.2f * e3; w3 = __expf(e3);
    }
    S0 += wave_sum(w0); S1 += wave_sum(w1);
    S2 += wave_sum(w2); S3 += wave_sum(w3);
    int k = 0;
    for (; k + 1 < cnt; k += 2) {
      int sa = ilanebcast(myidx, k);
      int sb = ilanebcast(myidx, k + 1);
      float wa0 = lanebcast(w0, k), wb0 = lanebcast(w0, k + 1);
      float wa1 = lanebcast(w1, k), wb1 = lanebcast(w1, k + 1);
      float wa2 = lanebcast(w2, k), wb2 = lanebcast(w2, k + 1);
      float wa3 = lanebcast(w3, k), wb3 = lanebcast(w3, k + 1);
      float va = x3[(size_t)sa * 64 + lane];
      float vb = x3[(size_t)sb * 64 + lane];
      acc0 = fmaf(wa0, va, acc0); acc1 = fmaf(wa1, va, acc1);
      acc2 = fmaf(wa2, va, acc2); acc3 = fmaf(wa3, va, acc3);
      acc0 = fmaf(wb0, vb, acc0); acc1 = fmaf(wb1, vb, acc1);
      acc2 = fmaf(wb2, vb, acc2); acc3 = fmaf(wb3, vb, acc3);
    }
    if (k < cnt) {
      int sa = ilanebcast(myidx, k);
      float wa0 = lanebcast(w0, k), wa1 = lanebcast(w1, k);
      float wa2 = lanebcast(w2, k), wa3 = lanebcast(w3, k);
      float va = x3[(size_t)sa * 64 + lane];
      acc0 = fmaf(wa0, va, acc0); acc1 = fmaf(wa1, va, acc1);
      acc2 = fmaf(wa2, va, acc2); acc3 = fmaf(wa3, va, acc3);
    }
  }
  float v[4] = {acc0 * (0.25f / S0), acc1 * (0.25f / S1),
                acc2 * (0.25f / S2), acc3 * (0.25f / S3)};
  size_t baseo = (size_t)node * 256 + lane;
#pragma unroll
  for (int h = 0; h < 4; h++) {
    ushort_t hb = f2bf(v[h]);
    Ahi[baseo + h * 64] = hb;
    Alo[baseo + h * 64] = f2bf(v[h] - b2f(hb));
  }
}

// ---------------- K5b: proj out = relu(agg[N,256] @ Wcat + b) via MFMA -----
__global__ __launch_bounds__(256) void k_gat_proj_mfma(
    const ushort_t* __restrict__ Ahi, const ushort_t* __restrict__ Alo,
    const ushort_t* __restrict__ Bh, const ushort_t* __restrict__ Bl,
    const float* __restrict__ bias, float* __restrict__ out, int n, int ntiles) {
  int tid = threadIdx.x, lane = tid & 63, wave = tid >> 6;
  int m = lane & 15, q = lane >> 4;
  float bv[4];
#pragma unroll
  for (int ct = 0; ct < 4; ct++) bv[ct] = bias[ct * 16 + m];
  for (int tile = blockIdx.x * 4 + wave; tile < ntiles; tile += gridDim.x * 4) {
    int ra = tile * 16 + m;
    if (ra >= n) ra = n - 1;
    const ushort_t* ahr = Ahi + (size_t)ra * 256;
    const ushort_t* alr = Alo + (size_t)ra * 256;
    f4 acc[4];
#pragma unroll
    for (int ct = 0; ct < 4; ct++) acc[ct] = (f4){0.f, 0.f, 0.f, 0.f};
#pragma unroll 2
    for (int kc = 0; kc < 8; kc++) {
      int ko = kc * 32 + q * 8;
      bf8 ah = *(const bf8*)(ahr + ko);
      bf8 al = *(const bf8*)(alr + ko);
#pragma unroll
      for (int ct = 0; ct < 4; ct++) {
        size_t boff = ((size_t)(ct * 8 + kc) * 64 + lane) * 8;
        bf8 bh = *(const bf8*)(Bh + boff);
        bf8 bl = *(const bf8*)(Bl + boff);
        acc[ct] = __builtin_amdgcn_mfma_f32_16x16x32_bf16(ah, bh, acc[ct], 0, 0, 0);
        acc[ct] = __builtin_amdgcn_mfma_f32_16x16x32_bf16(al, bh, acc[ct], 0, 0, 0);
        acc[ct] = __builtin_amdgcn_mfma_f32_16x16x32_bf16(ah, bl, acc[ct], 0, 0, 0);
      }
    }
#pragma unroll
    for (int r = 0; r < 4; r++) {
      int row = tile * 16 + q * 4 + r;
      if (row < n) {
#pragma unroll
        for (int ct = 0; ct < 4; ct++)
          out[(size_t)row * 64 + ct * 16 + m] = fmaxf(acc[ct][r] + bv[ct], 0.f);
      }
    }
  }
}

// ---------------- pooling ----------------
__global__ void k_gstart(const int* __restrict__ batch, int* gs, int n, int B) {
  int g = blockIdx.x * blockDim.x + threadIdx.x;
  if (g > B) return;
  int lo = 0, hi = n;
  while (lo < hi) {
    int mid = (lo + hi) >> 1;
    if (batch[mid] < g) lo = mid + 1; else hi = mid;
  }
  gs[g] = lo;
}

__global__ __launch_bounds__(256) void k_pool(const float* __restrict__ x,
                                              const int* __restrict__ gs,
                                              float* __restrict__ gvec, int B) {
  int g = (blockIdx.x * blockDim.x + threadIdx.x) >> 6;
  int lane = threadIdx.x & 63;
  if (g >= B) return;
  int s0 = gs[g], s1 = gs[g + 1];
  float sum = 0.0f, mx = -INFINITY;
  for (int nd = s0; nd < s1; ++nd) {
    float v = x[(size_t)nd * 64 + lane];
    sum += v;
    mx = fmaxf(mx, v);
  }
  int cnt = s1 - s0;
  float mean = sum / fmaxf((float)cnt, 1.0f);
  float mp = (cnt > 0) ? mx : 0.0f;
  gvec[g * 64 + lane] = mean + mp;
}

// ---------------- MLP head ----------------
__global__ __launch_bounds__(256) void k_mlp(const float* __restrict__ gvec,
                                             const float* __restrict__ w1,
                                             const float* __restrict__ b1,
                                             const float* __restrict__ w2,
                                             const float* __restrict__ b2,
                                             float* __restrict__ out, int B) {
  int g = blockIdx.x * blockDim.x + threadIdx.x;
  if (g >= B) return;
  float gv[64];
#pragma unroll
  for (int i = 0; i < 64; i++) gv[i] = gvec[g * 64 + i];
  float o0 = b2[0], o1 = b2[1];
  for (int j = 0; j < 32; j++) {
    float a = b1[j];
#pragma unroll
    for (int i = 0; i < 64; i++) a = fmaf(gv[i], w1[i * 32 + j], a);
    a = fmaxf(a, 0.0f);
    o0 = fmaf(a, w2[j * 2 + 0], o0);
    o1 = fmaf(a, w2[j * 2 + 1], o1);
  }
  out[g * 2 + 0] = o0;
  out[g * 2 + 1] = o1;
}

// ---------------- launch ----------------
extern "C" void kernel_launch(void* const* d_in, const int* in_sizes, int n_in,
                              void* d_out, int out_size, void* d_ws, size_t ws_size,
                              hipStream_t stream) {
  const float* x     = (const float*)d_in[0];
  const int*   ei    = (const int*)d_in[1];
  const int*   batch = (const int*)d_in[2];
  const float* w0 = (const float*)d_in[3];  const float* b0 = (const float*)d_in[4];
  const float* w1 = (const float*)d_in[5];  const float* b1 = (const float*)d_in[6];
  const float* w2 = (const float*)d_in[7];  const float* b2 = (const float*)d_in[8];
  const float* gat_w = (const float*)d_in[9];
  const float* att_s = (const float*)d_in[10];
  const float* att_d = (const float*)d_in[11];
  const float* gat_b = (const float*)d_in[12];
  const float* l1w = (const float*)d_in[13]; const float* l1b = (const float*)d_in[14];
  const float* l2w = (const float*)d_in[15]; const float* l2b = (const float*)d_in[16];

  const int N = in_sizes[0] / 128;
  const int E = in_sizes[1] / 2;
  const int B = out_size / 2;
  const int NT = (N + 15) / 16;

  char* ws = (char*)d_ws;
  size_t off = 0;
  auto alloc = [&](size_t bytes) -> void* {
    void* p = ws + off;
    off = (off + bytes + 255) & ~(size_t)255;
    return p;
  };
  int*      deg      = (int*)alloc((size_t)N * 4);
  int*      cursor   = (int*)alloc((size_t)N * 4);
  int*      rowstart = (int*)alloc((size_t)(N + 1) * 4);
  int*      colidx   = (int*)alloc((size_t)(E + N) * 4);
  float*    dinv     = (float*)alloc((size_t)N * 4);
  float*    hbuf     = (float*)alloc((size_t)N * 64 * 4);
  float*    act      = (float*)alloc((size_t)N * 64 * 4);
  float*    xg       = (float*)alloc((size_t)N * 64 * 4);
  ushort_t* Ahi      = (ushort_t*)alloc((size_t)N * 256 * 2);
  ushort_t* Alo      = (ushort_t*)alloc((size_t)N * 256 * 2);
  float*    a_src    = (float*)alloc((size_t)N * 4 * 4);
  float*    a_dst    = (float*)alloc((size_t)N * 4 * 4);
  float*    q_src    = (float*)alloc(4 * 64 * 4);
  float*    q_dst    = (float*)alloc(4 * 64 * 4);
  ushort_t* B0h      = (ushort_t*)alloc(4 * 4 * 64 * 8 * 2);
  ushort_t* B0l      = (ushort_t*)alloc(4 * 4 * 64 * 8 * 2);
  ushort_t* Bgh      = (ushort_t*)alloc(4 * 8 * 64 * 8 * 2);
  ushort_t* Bgl      = (ushort_t*)alloc(4 * 8 * 64 * 8 * 2);
  int*      gs       = (int*)alloc((size_t)(B + 1) * 4);
  float*    gvec     = (float*)alloc((size_t)B * 64 * 4);
  (void)ws_size; (void)n_in;

  // CSR build + weight prep
  k_initdeg<<<(N + 255) / 256, 256, 0, stream>>>(deg, N);
  k_count<<<(E + 255) / 256, 256, 0, stream>>>(ei + E, deg, E);
  k_scan<<<1, 1024, 0, stream>>>(deg, rowstart, cursor, N);
  k_dinv<<<(N + 255) / 256, 256, 0, stream>>>(deg, dinv, N);
  k_scatter<<<(E + N + 255) / 256, 256, 0, stream>>>(ei, ei + E, cursor, colidx, E, N);
  k_qpre<<<1, 256, 0, stream>>>(gat_w, att_s, att_d, q_src, q_dst);
  k_wswz0<<<1, 256, 0, stream>>>(w0, B0h, B0l);
  k_wswzg<<<1, 256, 0, stream>>>(gat_w, Bgh, Bgl);

  const int AGB = 2048;
  // K1: h0' = dinv * (x @ W0)  (MFMA)
  k_gemm0_mfma<<<1024, 256, 0, stream>>>(x, B0h, B0l, dinv, hbuf, N, NT);
  // K2: x1 = relu(dinv*agg(h0')+b0); h1' = dinv*(x1@W1)
  k_agg_gemm<<<AGB, 256, 0, stream>>>(hbuf, dinv, rowstart, colidx, b0, w1, act, N);
  // K3
  k_agg_gemm<<<AGB, 256, 0, stream>>>(act, dinv, rowstart, colidx, b1, w2, hbuf, N);
  // K4: x3 + attention logits
  k_agg_gatpre<<<AGB, 256, 0, stream>>>(hbuf, dinv, rowstart, colidx, b2,
                                        q_src, q_dst, xg, a_src, a_dst, N);
  // K5a: softmax-weighted gather in x-space -> bf16 hi/lo planes
  k_gat_gather<<<(N + 3) / 4, 256, 0, stream>>>(xg, a_src, a_dst, rowstart, colidx,
                                                Ahi, Alo, N);
  // K5b: projection via MFMA
  k_gat_proj_mfma<<<1024, 256, 0, stream>>>(Ahi, Alo, Bgh, Bgl, gat_b, act, N, NT);
  // pooling + head
  k_gstart<<<(B + 1 + 255) / 256, 256, 0, stream>>>(batch, gs, N, B);
  k_pool<<<(B + 3) / 4, 256, 0, stream>>>(act, gs, gvec, B);
  k_mlp<<<(B + 255) / 256, 256, 0, stream>>>(gvec, l1w, l1b, l2w, l2b, (float*)d_out, B);
}

// Round 6
// 463.856 us; speedup vs baseline: 2.7009x; 1.1561x over previous
//
#include <hip/hip_runtime.h>
#include <math.h>

typedef short bf8 __attribute__((ext_vector_type(8)));   // 8 bf16 in 4 VGPRs
typedef float f4 __attribute__((ext_vector_type(4)));
typedef unsigned short ushort_t;

// ---------------- helpers ----------------
__device__ __forceinline__ float lanebcast(float v, int l) {
  return __int_as_float(__builtin_amdgcn_readlane(__float_as_int(v), l));
}
__device__ __forceinline__ int ilanebcast(int v, int l) {
  return __builtin_amdgcn_readlane(v, l);
}

__device__ __forceinline__ float wave_sum(float v) {
#pragma unroll
  for (int off = 32; off > 0; off >>= 1) v += __shfl_xor(v, off, 64);
  return v;
}

__device__ __forceinline__ ushort_t f2bf(float x) {  // RNE fp32->bf16 bits
  unsigned int u = __float_as_uint(x);
  return (ushort_t)((u + 0x7fffu + ((u >> 16) & 1u)) >> 16);
}
__device__ __forceinline__ float b2f(ushort_t h) {
  return __uint_as_float(((unsigned int)h) << 16);
}

// ---------------- CSR build ----------------
__global__ void k_initdeg(int* deg, int n) {
  int i = blockIdx.x * blockDim.x + threadIdx.x;
  if (i < n) deg[i] = 1;  // self-loop
}

__global__ void k_count(const int* __restrict__ dst, int* deg, int E) {
  int e = blockIdx.x * blockDim.x + threadIdx.x;
  if (e < E) atomicAdd(&deg[dst[e]], 1);
}

// -------- 3-phase hierarchical exclusive scan (chunk = 1024 = 256thr x 4) ---
#define SCAN_CHUNK 1024

__global__ __launch_bounds__(256) void k_scan_local(
    const int* __restrict__ deg, int* __restrict__ rowstart,
    int* __restrict__ blocksum, int n) {
  __shared__ int smem[256];
  int b = blockIdx.x, tid = threadIdx.x;
  int base = b * SCAN_CHUNK + tid * 4;
  int v[4];
#pragma unroll
  for (int p = 0; p < 4; p++) { int i = base + p; v[p] = (i < n) ? deg[i] : 0; }
  int s = v[0] + v[1] + v[2] + v[3];
  smem[tid] = s;
  __syncthreads();
  for (int off = 1; off < 256; off <<= 1) {
    int t = (tid >= off) ? smem[tid - off] : 0;
    __syncthreads();
    smem[tid] += t;
    __syncthreads();
  }
  int excl = smem[tid] - s;
  if (tid == 255) blocksum[b] = smem[255];
#pragma unroll
  for (int p = 0; p < 4; p++) {
    int i = base + p;
    if (i < n) rowstart[i] = excl;
    excl += v[p];
  }
}

// spine: nb <= 256 chunks
__global__ __launch_bounds__(256) void k_scan_spine(
    const int* __restrict__ blocksum, int* __restrict__ blockoff, int nb,
    int* __restrict__ rowstart, int n) {
  __shared__ int smem[256];
  int tid = threadIdx.x;
  int v = (tid < nb) ? blocksum[tid] : 0;
  smem[tid] = v;
  __syncthreads();
  for (int off = 1; off < 256; off <<= 1) {
    int t = (tid >= off) ? smem[tid - off] : 0;
    __syncthreads();
    smem[tid] += t;
    __syncthreads();
  }
  if (tid < nb) blockoff[tid] = smem[tid] - v;
  if (tid == 255) rowstart[n] = smem[255];
}

__global__ __launch_bounds__(256) void k_scan_add(
    const int* __restrict__ deg, int* __restrict__ rowstart,
    int* __restrict__ cursor, float* __restrict__ dinv,
    const int* __restrict__ blockoff, int n) {
  int b = blockIdx.x, tid = threadIdx.x;
  int off = blockoff[b];
  int base = b * SCAN_CHUNK + tid * 4;
#pragma unroll
  for (int p = 0; p < 4; p++) {
    int i = base + p;
    if (i < n) {
      int r = rowstart[i] + off;
      rowstart[i] = r;
      cursor[i] = r;
      dinv[i] = 1.0f / sqrtf((float)deg[i]);
    }
  }
}

__global__ void k_scatter(const int* __restrict__ ei_src, const int* __restrict__ ei_dst,
                          int* cursor, int* colidx, int E, int n) {
  int e = blockIdx.x * blockDim.x + threadIdx.x;
  if (e >= E + n) return;
  int s, d;
  if (e < E) { s = ei_src[e]; d = ei_dst[e]; }
  else       { s = e - E; d = s; }
  int pos = atomicAdd(&cursor[d], 1);
  colidx[pos] = s;
}

// ---------------- weight swizzle into MFMA B-fragment layout ----------------
// B-frag for 16x16x32: lane holds B[k=(lane>>4)*8+j][n=lane&15], j=0..7.
// Buffer layout: frag[( (ct*KC + kc)*64 + lane )*8 + j], hi/lo bf16 planes.

// W0 [128,64] direct
__global__ void k_wswz0(const float* __restrict__ W, ushort_t* __restrict__ Bh,
                        ushort_t* __restrict__ Bl) {
  for (int e = threadIdx.x; e < 4 * 4 * 64; e += 256) {
    int lane = e & 63, kc = (e >> 6) & 3, ct = e >> 8;
    int k0 = kc * 32 + (lane >> 4) * 8;
    int col = ct * 16 + (lane & 15);
#pragma unroll
    for (int j = 0; j < 8; j++) {
      float w = W[(k0 + j) * 64 + col];
      ushort_t h = f2bf(w);
      Bh[(size_t)e * 8 + j] = h;
      Bl[(size_t)e * 8 + j] = f2bf(w - b2f(h));
    }
  }
}

// Wg_cat [256,64]: Wcat[k=h*64+c][col] = gat_w[c*256 + h*64 + col]
__global__ void k_wswzg(const float* __restrict__ W, ushort_t* __restrict__ Bh,
                        ushort_t* __restrict__ Bl) {
  for (int e = threadIdx.x; e < 4 * 8 * 64; e += 256) {
    int lane = e & 63, kc = (e >> 6) & 7, ct = e >> 9;
    int k0 = kc * 32 + (lane >> 4) * 8;
    int col = ct * 16 + (lane & 15);
#pragma unroll
    for (int j = 0; j < 8; j++) {
      int k = k0 + j;
      float w = W[(k & 63) * 256 + (k >> 6) * 64 + col];
      ushort_t h = f2bf(w);
      Bh[(size_t)e * 8 + j] = h;
      Bl[(size_t)e * 8 + j] = f2bf(w - b2f(h));
    }
  }
}

// ---------------- K1: H0'[N,64] = dinv[n] * (X[N,128] @ W0) via MFMA -------
__global__ __launch_bounds__(256) void k_gemm0_mfma(
    const float* __restrict__ X, const ushort_t* __restrict__ Bh,
    const ushort_t* __restrict__ Bl, const float* __restrict__ dinv,
    float* __restrict__ H, int n, int ntiles) {
  int tid = threadIdx.x, lane = tid & 63, wave = tid >> 6;
  int m = lane & 15, q = lane >> 4;
  for (int tile = blockIdx.x * 4 + wave; tile < ntiles; tile += gridDim.x * 4) {
    int ra = tile * 16 + m;
    if (ra >= n) ra = n - 1;
    const float* xrow = X + (size_t)ra * 128;
    f4 acc[4];
#pragma unroll
    for (int ct = 0; ct < 4; ct++) acc[ct] = (f4){0.f, 0.f, 0.f, 0.f};
#pragma unroll 2
    for (int kc = 0; kc < 4; kc++) {
      int ko = kc * 32 + q * 8;
      float4 xa = *(const float4*)(xrow + ko);
      float4 xb = *(const float4*)(xrow + ko + 4);
      float f[8] = {xa.x, xa.y, xa.z, xa.w, xb.x, xb.y, xb.z, xb.w};
      union { ushort_t u[8]; bf8 v; } Uh, Ul;
#pragma unroll
      for (int j = 0; j < 8; j++) {
        ushort_t h = f2bf(f[j]);
        Uh.u[j] = h;
        Ul.u[j] = f2bf(f[j] - b2f(h));
      }
#pragma unroll
      for (int ct = 0; ct < 4; ct++) {
        size_t boff = ((size_t)(ct * 4 + kc) * 64 + lane) * 8;
        bf8 bh = *(const bf8*)(Bh + boff);
        bf8 bl = *(const bf8*)(Bl + boff);
        acc[ct] = __builtin_amdgcn_mfma_f32_16x16x32_bf16(Uh.v, bh, acc[ct], 0, 0, 0);
        acc[ct] = __builtin_amdgcn_mfma_f32_16x16x32_bf16(Ul.v, bh, acc[ct], 0, 0, 0);
        acc[ct] = __builtin_amdgcn_mfma_f32_16x16x32_bf16(Uh.v, bl, acc[ct], 0, 0, 0);
      }
    }
#pragma unroll
    for (int r = 0; r < 4; r++) {
      int row = tile * 16 + q * 4 + r;
      if (row < n) {
        float dv = dinv[row];
#pragma unroll
        for (int ct = 0; ct < 4; ct++)
          H[(size_t)row * 64 + ct * 16 + m] = acc[ct][r] * dv;
      }
    }
  }
}

// ---------------- gather core ----------------
__device__ __forceinline__ float gather_sum(const float* __restrict__ h_in,
                                            const int* __restrict__ colidx,
                                            int s0, int s1, int lane) {
  float acc = 0.0f, accB = 0.0f;
  for (int base = s0; base < s1; base += 64) {
    int cnt = min(64, s1 - base);
    int myidx = (lane < cnt) ? colidx[base + lane] : 0;
    int k = 0;
    for (; k + 3 < cnt; k += 4) {
      int sa = ilanebcast(myidx, k);
      int sb = ilanebcast(myidx, k + 1);
      int sc = ilanebcast(myidx, k + 2);
      int sd = ilanebcast(myidx, k + 3);
      float va = h_in[(size_t)sa * 64 + lane];
      float vb = h_in[(size_t)sb * 64 + lane];
      float vc = h_in[(size_t)sc * 64 + lane];
      float vd = h_in[(size_t)sd * 64 + lane];
      acc += va; accB += vb; acc += vc; accB += vd;
    }
    for (; k < cnt; k++) {
      int sa = ilanebcast(myidx, k);
      acc += h_in[(size_t)sa * 64 + lane];
    }
  }
  return acc + accB;
}

// ---------------- K2/K3: fused GCN agg + next GEMM (readlane GEMV) --------
__global__ __launch_bounds__(256) void k_agg_gemm(
    const float* __restrict__ h_in, const float* __restrict__ dinv,
    const int* __restrict__ rowstart, const int* __restrict__ colidx,
    const float* __restrict__ bias, const float* __restrict__ Wn,
    float* __restrict__ h_out, int n) {
  __shared__ float lds_w[64 * 64];
  int tid = threadIdx.x;
  for (int idx = tid; idx < 64 * 64; idx += 256) lds_w[idx] = Wn[idx];
  __syncthreads();
  int lane = tid & 63;
  float bv = bias[lane];
  int gw = blockIdx.x * 4 + (tid >> 6);
  int nw = gridDim.x * 4;
  for (int node = gw; node < n; node += nw) {
    int s0 = rowstart[node], s1 = rowstart[node + 1];
    float acc = gather_sum(h_in, colidx, s0, s1, lane);
    float dvn = dinv[node];
    float x1 = fmaxf(fmaf(dvn, acc, bv), 0.0f);
    float o = 0.0f;
#pragma unroll 8
    for (int k = 0; k < 64; k++)
      o = fmaf(lanebcast(x1, k), lds_w[k * 64 + lane], o);
    h_out[(size_t)node * 64 + lane] = o * dvn;
  }
}

// ---------------- K4: GCN layer-2 agg + GAT attention logits ----------------
__global__ __launch_bounds__(256) void k_agg_gatpre(
    const float* __restrict__ h_in, const float* __restrict__ dinv,
    const int* __restrict__ rowstart, const int* __restrict__ colidx,
    const float* __restrict__ bias,
    const float* __restrict__ q_src, const float* __restrict__ q_dst,
    float* __restrict__ x3, float* __restrict__ a_src, float* __restrict__ a_dst,
    int n) {
  int tid = threadIdx.x;
  int lane = tid & 63;
  float bv = bias[lane];
  float qs[4], qd[4];
#pragma unroll
  for (int h = 0; h < 4; h++) {
    qs[h] = q_src[h * 64 + lane];
    qd[h] = q_dst[h * 64 + lane];
  }
  int gw = blockIdx.x * 4 + (tid >> 6);
  int nw = gridDim.x * 4;
  for (int node = gw; node < n; node += nw) {
    int s0 = rowstart[node], s1 = rowstart[node + 1];
    float acc = gather_sum(h_in, colidx, s0, s1, lane);
    float xv = fmaxf(fmaf(dinv[node], acc, bv), 0.0f);
    x3[(size_t)node * 64 + lane] = xv;
    float ps[4], pd[4];
#pragma unroll
    for (int h = 0; h < 4; h++) {
      ps[h] = wave_sum(xv * qs[h]);
      pd[h] = wave_sum(xv * qd[h]);
    }
    if (lane == 0) {
      *(float4*)&a_src[(size_t)node * 4] = make_float4(ps[0], ps[1], ps[2], ps[3]);
      *(float4*)&a_dst[(size_t)node * 4] = make_float4(pd[0], pd[1], pd[2], pd[3]);
    }
  }
}

// q[h][k] = sum_c W[k, h*64+c] * att[h][c]
__global__ void k_qpre(const float* __restrict__ W, const float* __restrict__ att_s,
                       const float* __restrict__ att_d,
                       float* __restrict__ q_src, float* __restrict__ q_dst) {
  int t = threadIdx.x;
  int h = t >> 6, k = t & 63;
  float ss = 0.0f, sd = 0.0f;
  for (int c = 0; c < 64; c++) {
    float w = W[k * 256 + h * 64 + c];
    ss = fmaf(w, att_s[h * 64 + c], ss);
    sd = fmaf(w, att_d[h * 64 + c], sd);
  }
  q_src[h * 64 + k] = ss;
  q_dst[h * 64 + k] = sd;
}

// ---------------- K5a: GAT softmax-aggregate in x-space ----------
__global__ __launch_bounds__(256) void k_gat_gather(
    const float* __restrict__ x3, const float* __restrict__ a_src,
    const float* __restrict__ a_dst, const int* __restrict__ rowstart,
    const int* __restrict__ colidx, ushort_t* __restrict__ Ahi,
    ushort_t* __restrict__ Alo, int n) {
  int node = (blockIdx.x * blockDim.x + threadIdx.x) >> 6;
  int lane = threadIdx.x & 63;
  if (node >= n) return;
  const float4 adv = *(const float4*)&a_dst[(size_t)node * 4];
  int s0 = rowstart[node], s1 = rowstart[node + 1];
  float acc0 = 0, acc1 = 0, acc2 = 0, acc3 = 0;
  float S0 = 0, S1 = 0, S2 = 0, S3 = 0;
  for (int base = s0; base < s1; base += 64) {
    int cnt = min(64, s1 - base);
    bool act = (lane < cnt);
    int myidx = act ? colidx[base + lane] : 0;
    float w0 = 0, w1 = 0, w2 = 0, w3 = 0;
    if (act) {
      const float4 as = *(const float4*)&a_src[(size_t)myidx * 4];
      float e0 = as.x + adv.x; e0 = (e0 > 0.f) ? e0 : 0.2f * e0; w0 = __expf(e0);
      float e1 = as.y + adv.y; e1 = (e1 > 0.f) ? e1 : 0.2f * e1; w1 = __expf(e1);
      float e2 = as.z + adv.z; e2 = (e2 > 0.f) ? e2 : 0.2f * e2; w2 = __expf(e2);
      float e3 = as.w + adv.w; e3 = (e3 > 0.f) ? e3 : 0.2f * e3; w3 = __expf(e3);
    }
    S0 += wave_sum(w0); S1 += wave_sum(w1);
    S2 += wave_sum(w2); S3 += wave_sum(w3);
    int k = 0;
    for (; k + 1 < cnt; k += 2) {
      int sa = ilanebcast(myidx, k);
      int sb = ilanebcast(myidx, k + 1);
      float wa0 = lanebcast(w0, k), wb0 = lanebcast(w0, k + 1);
      float wa1 = lanebcast(w1, k), wb1 = lanebcast(w1, k + 1);
      float wa2 = lanebcast(w2, k), wb2 = lanebcast(w2, k + 1);
      float wa3 = lanebcast(w3, k), wb3 = lanebcast(w3, k + 1);
      float va = x3[(size_t)sa * 64 + lane];
      float vb = x3[(size_t)sb * 64 + lane];
      acc0 = fmaf(wa0, va, acc0); acc1 = fmaf(wa1, va, acc1);
      acc2 = fmaf(wa2, va, acc2); acc3 = fmaf(wa3, va, acc3);
      acc0 = fmaf(wb0, vb, acc0); acc1 = fmaf(wb1, vb, acc1);
      acc2 = fmaf(wb2, vb, acc2); acc3 = fmaf(wb3, vb, acc3);
    }
    if (k < cnt) {
      int sa = ilanebcast(myidx, k);
      float wa0 = lanebcast(w0, k), wa1 = lanebcast(w1, k);
      float wa2 = lanebcast(w2, k), wa3 = lanebcast(w3, k);
      float va = x3[(size_t)sa * 64 + lane];
      acc0 = fmaf(wa0, va, acc0); acc1 = fmaf(wa1, va, acc1);
      acc2 = fmaf(wa2, va, acc2); acc3 = fmaf(wa3, va, acc3);
    }
  }
  float v[4] = {acc0 * (0.25f / S0), acc1 * (0.25f / S1),
                acc2 * (0.25f / S2), acc3 * (0.25f / S3)};
  size_t baseo = (size_t)node * 256 + lane;
#pragma unroll
  for (int h = 0; h < 4; h++) {
    ushort_t hb = f2bf(v[h]);
    Ahi[baseo + h * 64] = hb;
    Alo[baseo + h * 64] = f2bf(v[h] - b2f(hb));
  }
}

// ---------------- K5b: proj out = relu(agg[N,256] @ Wcat + b) via MFMA -----
__global__ __launch_bounds__(256) void k_gat_proj_mfma(
    const ushort_t* __restrict__ Ahi, const ushort_t* __restrict__ Alo,
    const ushort_t* __restrict__ Bh, const ushort_t* __restrict__ Bl,
    const float* __restrict__ bias, float* __restrict__ out, int n, int ntiles) {
  int tid = threadIdx.x, lane = tid & 63, wave = tid >> 6;
  int m = lane & 15, q = lane >> 4;
  float bv[4];
#pragma unroll
  for (int ct = 0; ct < 4; ct++) bv[ct] = bias[ct * 16 + m];
  for (int tile = blockIdx.x * 4 + wave; tile < ntiles; tile += gridDim.x * 4) {
    int ra = tile * 16 + m;
    if (ra >= n) ra = n - 1;
    const ushort_t* ahr = Ahi + (size_t)ra * 256;
    const ushort_t* alr = Alo + (size_t)ra * 256;
    f4 acc[4];
#pragma unroll
    for (int ct = 0; ct < 4; ct++) acc[ct] = (f4){0.f, 0.f, 0.f, 0.f};
#pragma unroll 2
    for (int kc = 0; kc < 8; kc++) {
      int ko = kc * 32 + q * 8;
      bf8 ah = *(const bf8*)(ahr + ko);
      bf8 al = *(const bf8*)(alr + ko);
#pragma unroll
      for (int ct = 0; ct < 4; ct++) {
        size_t boff = ((size_t)(ct * 8 + kc) * 64 + lane) * 8;
        bf8 bh = *(const bf8*)(Bh + boff);
        bf8 bl = *(const bf8*)(Bl + boff);
        acc[ct] = __builtin_amdgcn_mfma_f32_16x16x32_bf16(ah, bh, acc[ct], 0, 0, 0);
        acc[ct] = __builtin_amdgcn_mfma_f32_16x16x32_bf16(al, bh, acc[ct], 0, 0, 0);
        acc[ct] = __builtin_amdgcn_mfma_f32_16x16x32_bf16(ah, bl, acc[ct], 0, 0, 0);
      }
    }
#pragma unroll
    for (int r = 0; r < 4; r++) {
      int row = tile * 16 + q * 4 + r;
      if (row < n) {
#pragma unroll
        for (int ct = 0; ct < 4; ct++)
          out[(size_t)row * 64 + ct * 16 + m] = fmaxf(acc[ct][r] + bv[ct], 0.f);
      }
    }
  }
}

// ---------------- pooling ----------------
__global__ void k_gstart(const int* __restrict__ batch, int* gs, int n, int B) {
  int g = blockIdx.x * blockDim.x + threadIdx.x;
  if (g > B) return;
  int lo = 0, hi = n;
  while (lo < hi) {
    int mid = (lo + hi) >> 1;
    if (batch[mid] < g) lo = mid + 1; else hi = mid;
  }
  gs[g] = lo;
}

__global__ __launch_bounds__(256) void k_pool(const float* __restrict__ x,
                                              const int* __restrict__ gs,
                                              float* __restrict__ gvec, int B) {
  int g = (blockIdx.x * blockDim.x + threadIdx.x) >> 6;
  int lane = threadIdx.x & 63;
  if (g >= B) return;
  int s0 = gs[g], s1 = gs[g + 1];
  float sum = 0.0f, mx = -INFINITY;
  for (int nd = s0; nd < s1; ++nd) {
    float v = x[(size_t)nd * 64 + lane];
    sum += v;
    mx = fmaxf(mx, v);
  }
  int cnt = s1 - s0;
  float mean = sum / fmaxf((float)cnt, 1.0f);
  float mp = (cnt > 0) ? mx : 0.0f;
  gvec[g * 64 + lane] = mean + mp;
}

// ---------------- MLP head ----------------
__global__ __launch_bounds__(256) void k_mlp(const float* __restrict__ gvec,
                                             const float* __restrict__ w1,
                                             const float* __restrict__ b1,
                                             const float* __restrict__ w2,
                                             const float* __restrict__ b2,
                                             float* __restrict__ out, int B) {
  int g = blockIdx.x * blockDim.x + threadIdx.x;
  if (g >= B) return;
  float gv[64];
#pragma unroll
  for (int i = 0; i < 64; i++) gv[i] = gvec[g * 64 + i];
  float o0 = b2[0], o1 = b2[1];
  for (int j = 0; j < 32; j++) {
    float a = b1[j];
#pragma unroll
    for (int i = 0; i < 64; i++) a = fmaf(gv[i], w1[i * 32 + j], a);
    a = fmaxf(a, 0.0f);
    o0 = fmaf(a, w2[j * 2 + 0], o0);
    o1 = fmaf(a, w2[j * 2 + 1], o1);
  }
  out[g * 2 + 0] = o0;
  out[g * 2 + 1] = o1;
}

// ---------------- launch ----------------
extern "C" void kernel_launch(void* const* d_in, const int* in_sizes, int n_in,
                              void* d_out, int out_size, void* d_ws, size_t ws_size,
                              hipStream_t stream) {
  const float* x     = (const float*)d_in[0];
  const int*   ei    = (const int*)d_in[1];
  const int*   batch = (const int*)d_in[2];
  const float* w0 = (const float*)d_in[3];  const float* b0 = (const float*)d_in[4];
  const float* w1 = (const float*)d_in[5];  const float* b1 = (const float*)d_in[6];
  const float* w2 = (const float*)d_in[7];  const float* b2 = (const float*)d_in[8];
  const float* gat_w = (const float*)d_in[9];
  const float* att_s = (const float*)d_in[10];
  const float* att_d = (const float*)d_in[11];
  const float* gat_b = (const float*)d_in[12];
  const float* l1w = (const float*)d_in[13]; const float* l1b = (const float*)d_in[14];
  const float* l2w = (const float*)d_in[15]; const float* l2b = (const float*)d_in[16];

  const int N = in_sizes[0] / 128;
  const int E = in_sizes[1] / 2;
  const int B = out_size / 2;
  const int NT = (N + 15) / 16;
  const int NB = (N + SCAN_CHUNK - 1) / SCAN_CHUNK;

  char* ws = (char*)d_ws;
  size_t off = 0;
  auto alloc = [&](size_t bytes) -> void* {
    void* p = ws + off;
    off = (off + bytes + 255) & ~(size_t)255;
    return p;
  };
  int*      deg      = (int*)alloc((size_t)N * 4);
  int*      cursor   = (int*)alloc((size_t)N * 4);
  int*      rowstart = (int*)alloc((size_t)(N + 1) * 4);
  int*      colidx   = (int*)alloc((size_t)(E + N) * 4);
  float*    dinv     = (float*)alloc((size_t)N * 4);
  int*      blocksum = (int*)alloc((size_t)NB * 4);
  int*      blockoff = (int*)alloc((size_t)NB * 4);
  float*    hbuf     = (float*)alloc((size_t)N * 64 * 4);
  float*    act      = (float*)alloc((size_t)N * 64 * 4);
  float*    xg       = (float*)alloc((size_t)N * 64 * 4);
  ushort_t* Ahi      = (ushort_t*)alloc((size_t)N * 256 * 2);
  ushort_t* Alo      = (ushort_t*)alloc((size_t)N * 256 * 2);
  float*    a_src    = (float*)alloc((size_t)N * 4 * 4);
  float*    a_dst    = (float*)alloc((size_t)N * 4 * 4);
  float*    q_src    = (float*)alloc(4 * 64 * 4);
  float*    q_dst    = (float*)alloc(4 * 64 * 4);
  ushort_t* B0h      = (ushort_t*)alloc(4 * 4 * 64 * 8 * 2);
  ushort_t* B0l      = (ushort_t*)alloc(4 * 4 * 64 * 8 * 2);
  ushort_t* Bgh      = (ushort_t*)alloc(4 * 8 * 64 * 8 * 2);
  ushort_t* Bgl      = (ushort_t*)alloc(4 * 8 * 64 * 8 * 2);
  int*      gs       = (int*)alloc((size_t)(B + 1) * 4);
  float*    gvec     = (float*)alloc((size_t)B * 64 * 4);
  (void)ws_size; (void)n_in;

  // CSR build + weight prep
  k_initdeg<<<(N + 255) / 256, 256, 0, stream>>>(deg, N);
  k_count<<<(E + 255) / 256, 256, 0, stream>>>(ei + E, deg, E);
  k_scan_local<<<NB, 256, 0, stream>>>(deg, rowstart, blocksum, N);
  k_scan_spine<<<1, 256, 0, stream>>>(blocksum, blockoff, NB, rowstart, N);
  k_scan_add<<<NB, 256, 0, stream>>>(deg, rowstart, cursor, dinv, blockoff, N);
  k_scatter<<<(E + N + 255) / 256, 256, 0, stream>>>(ei, ei + E, cursor, colidx, E, N);
  k_qpre<<<1, 256, 0, stream>>>(gat_w, att_s, att_d, q_src, q_dst);
  k_wswz0<<<1, 256, 0, stream>>>(w0, B0h, B0l);
  k_wswzg<<<1, 256, 0, stream>>>(gat_w, Bgh, Bgl);

  const int AGB = 2048;
  // K1: h0' = dinv * (x @ W0)  (MFMA)
  k_gemm0_mfma<<<1024, 256, 0, stream>>>(x, B0h, B0l, dinv, hbuf, N, NT);
  // K2: x1 = relu(dinv*agg(h0')+b0); h1' = dinv*(x1@W1)
  k_agg_gemm<<<AGB, 256, 0, stream>>>(hbuf, dinv, rowstart, colidx, b0, w1, act, N);
  // K3
  k_agg_gemm<<<AGB, 256, 0, stream>>>(act, dinv, rowstart, colidx, b1, w2, hbuf, N);
  // K4: x3 + attention logits
  k_agg_gatpre<<<AGB, 256, 0, stream>>>(hbuf, dinv, rowstart, colidx, b2,
                                        q_src, q_dst, xg, a_src, a_dst, N);
  // K5a: softmax-weighted gather in x-space -> bf16 hi/lo planes
  k_gat_gather<<<(N + 3) / 4, 256, 0, stream>>>(xg, a_src, a_dst, rowstart, colidx,
                                                Ahi, Alo, N);
  // K5b: projection via MFMA
  k_gat_proj_mfma<<<1024, 256, 0, stream>>>(Ahi, Alo, Bgh, Bgl, gat_b, act, N, NT);
  // pooling + head
  k_gstart<<<(B + 1 + 255) / 256, 256, 0, stream>>>(batch, gs, N, B);
  k_pool<<<(B + 3) / 4, 256, 0, stream>>>(act, gs, gvec, B);
  k_mlp<<<(B + 255) / 256, 256, 0, stream>>>(gvec, l1w, l1b, l2w, l2b, (float*)d_out, B);
}